// Round 14
// baseline (105.733 us; speedup 1.0000x reference)
//
#include <hip/hip_runtime.h>
#include <cstdint>

typedef unsigned short u16;
typedef __attribute__((ext_vector_type(2))) float f32x2;
typedef __attribute__((ext_vector_type(4))) float f32x4;
typedef __attribute__((ext_vector_type(8))) short bf16x8;
typedef __attribute__((ext_vector_type(4))) u16 u16x4;

#define B_C 2
#define T_C 2048
#define H_C 16
#define KV_C 4

__device__ __forceinline__ u16 f2bf(float f) {
  unsigned u = __builtin_bit_cast(unsigned, f);
  u = (u + 0x7fffu + ((u >> 16) & 1u)) >> 16;
  return (u16)u;
}

__device__ __forceinline__ unsigned cvtpk(float a, float b) {
  unsigned r;
  asm("v_cvt_pk_bf16_f32 %0, %1, %2" : "=v"(r) : "v"(a), "v"(b));
  return r;
}

#define GLL16(src, dst)                                                     \
  __builtin_amdgcn_global_load_lds(                                         \
      (__attribute__((address_space(1))) void*)(src),                       \
      (__attribute__((address_space(3))) void*)(dst), 16, 0, 0)

// ---------- fused prep: x->bf16, 4 weight transposes, cos/sin table ----------
__global__ void k_prep(const float* __restrict__ x, u16* __restrict__ xb,
                       const float* __restrict__ wq, const float* __restrict__ wk,
                       const float* __restrict__ wv, const float* __restrict__ wo,
                       u16* __restrict__ wqkvT, u16* __restrict__ woT,
                       f32x2* __restrict__ tab) {
  __shared__ float t[32][33];
  const int bid = blockIdx.x, tid = threadIdx.x;
  if (bid < 4096) {
    int i = bid * 256 + tid;
    f32x4 v = *(const f32x4*)(x + (size_t)i * 4);
    u16x4 o;
    o[0] = f2bf(v[0]); o[1] = f2bf(v[1]); o[2] = f2bf(v[2]); o[3] = f2bf(v[3]);
    *(u16x4*)(xb + (size_t)i * 4) = o;
  } else if (bid < 6656) {
    const float* in; u16* out; int N, lb;
    if (bid < 5120)      { in = wq; out = wqkvT;               N = 1024; lb = bid - 4096; }
    else if (bid < 5376) { in = wk; out = wqkvT + 1024 * 1024; N = 256;  lb = bid - 5120; }
    else if (bid < 5632) { in = wv; out = wqkvT + 1280 * 1024; N = 256;  lb = bid - 5376; }
    else                 { in = wo; out = woT;                 N = 1024; lb = bid - 5632; }
    const int kb = (lb & 31) * 32, nb = (lb >> 5) * 32;
    const int tx = tid & 31, ty = tid >> 5;
#pragma unroll
    for (int i = 0; i < 32; i += 8) t[ty + i][tx] = in[(size_t)(kb + ty + i) * N + nb + tx];
    __syncthreads();
#pragma unroll
    for (int i = 0; i < 32; i += 8) out[(size_t)(nb + ty + i) * 1024 + kb + tx] = f2bf(t[tx][ty + i]);
  } else {
    int idx = (bid - 6656) * 256 + tid;  // t*32 + i
    int i = idx & 31, tt = idx >> 5;
    float ang = (float)tt * exp2f(-(float)(2 * i) * (13.28771237954945f / 64.0f));
    float sn, cs; sincosf(ang, &sn, &cs);
    f32x2 v; v.x = cs; v.y = sn;
    tab[idx] = v;
  }
}

// ---------- GEMM1: 64x128 tile, 3-buf counted-vmcnt, fused RoPE epilogue ----------
__global__ __launch_bounds__(256, 3) void k_gemm_qkv(
    const u16* __restrict__ A, const u16* __restrict__ Bt,
    const f32x2* __restrict__ tab,
    u16* __restrict__ qb_, u16* __restrict__ kb_, u16* __restrict__ vT_) {
  constexpr int BK = 32, K = 1024, NT = K / BK;
  __shared__ u16 As[3][64 * BK];
  __shared__ u16 Bs[3][128 * BK];
  const int tid = threadIdx.x;
  const int lane = tid & 63, wid = tid >> 6;
  const int wr = wid >> 1, wc = wid & 1;
  const int l15 = lane & 15, lhi = lane >> 4;
  const int bm = blockIdx.x * 64, bn = blockIdx.y * 128;
  const int srow = tid >> 2, scol = (tid & 3) * 8;
  const u16* ga = A + (size_t)(bm + srow) * K + scol;
  const u16* gb = Bt + (size_t)(bn + srow) * K + scol;
  f32x4 acc[2][4] = {};
  const int aoff = (wr * 32 + l15) * BK + lhi * 8;
  const int boff = (wc * 64 + l15) * BK + lhi * 8;
#pragma unroll
  for (int p = 0; p < 2; p++) {
    GLL16(ga + p * BK, &As[p][tid * 8]);
    GLL16(gb + p * BK, &Bs[p][tid * 8]);
    GLL16(gb + (size_t)64 * K + p * BK, &Bs[p][2048 + tid * 8]);
  }
  int cur = 0, nxt = 2;
  for (int k = 0; k < NT; ++k) {
    if (k + 1 < NT) asm volatile("s_waitcnt vmcnt(3)" ::: "memory");
    else            asm volatile("s_waitcnt vmcnt(0)" ::: "memory");
    __builtin_amdgcn_s_barrier();
    if (k + 2 < NT) {
      const int k2 = (k + 2) * BK;
      GLL16(ga + k2, &As[nxt][tid * 8]);
      GLL16(gb + k2, &Bs[nxt][tid * 8]);
      GLL16(gb + (size_t)64 * K + k2, &Bs[nxt][2048 + tid * 8]);
    }
    bf16x8 af[2], bfr[4];
#pragma unroll
    for (int i = 0; i < 2; i++) af[i] = *(const bf16x8*)&As[cur][aoff + i * 16 * BK];
#pragma unroll
    for (int j = 0; j < 4; j++) bfr[j] = *(const bf16x8*)&Bs[cur][boff + j * 16 * BK];
#pragma unroll
    for (int i = 0; i < 2; i++)
#pragma unroll
      for (int j = 0; j < 4; j++)
        acc[i][j] = __builtin_amdgcn_mfma_f32_16x16x32_bf16(af[i], bfr[j], acc[i][j], 0, 0, 0);
    cur = (cur == 2) ? 0 : cur + 1;
    nxt = (nxt == 2) ? 0 : nxt + 1;
  }
  // ---- fused epilogue ----
  const int crow0 = bm + wr * 32 + lhi * 4;
  const int bsel = (blockIdx.x >= 32) ? 1 : 0;
  const int hg = (bn >> 6) + wc;
  if (blockIdx.y >= 10) {
    u16* dst = vT_ + ((size_t)(bsel * KV_C + (hg - 20)) * 64) * T_C;
#pragma unroll
    for (int j = 0; j < 4; j++) {
      const int d = l15 + j * 16;
#pragma unroll
      for (int i = 0; i < 2; i++) {
        const int t2 = (crow0 + i * 16) & 2047;
        u16x4 pk;
#pragma unroll
        for (int r = 0; r < 4; r++) pk[r] = f2bf(acc[i][j][r]);
        *(u16x4*)&dst[(size_t)d * T_C + t2] = pk;
      }
    }
  } else {
    const bool isq = (blockIdx.y < 8);
    u16* dst = isq ? (qb_ + ((size_t)(bsel * H_C + hg) * T_C) * 64)
                   : (kb_ + ((size_t)(bsel * KV_C + (hg - 16)) * T_C) * 64);
    const float sc = isq ? (0.125f * 1.4426950408889634f) : 1.0f;
    const int par = l15 & 1;
#pragma unroll
    for (int j = 0; j < 4; j++) {
      const int d = l15 + j * 16;
      const int ir = (l15 >> 1) + j * 8;
#pragma unroll
      for (int i = 0; i < 2; i++)
#pragma unroll
        for (int r = 0; r < 4; r++) {
          const int t2 = (crow0 + i * 16 + r) & 2047;
          float v = acc[i][j][r];
          float p = __shfl_xor(v, 1, 64);
          f32x2 cs = tab[t2 * 32 + ir];
          float sgn = par ? cs.y : -cs.y;
          dst[(size_t)t2 * 64 + d] = f2bf((v * cs.x + p * sgn) * sc);
        }
    }
  }
}

// ---------- GEMM2: 64x128 tile, 3-buf counted-vmcnt ----------
__global__ __launch_bounds__(256, 3) void k_gemm_bt(
    const u16* __restrict__ A, const u16* __restrict__ Bt, float* __restrict__ C,
    int M, int N, int K) {
  constexpr int BK = 32;
  __shared__ u16 As[3][64 * BK];
  __shared__ u16 Bs[3][128 * BK];
  const int tid = threadIdx.x;
  const int lane = tid & 63, wid = tid >> 6;
  const int wr = wid >> 1, wc = wid & 1;
  const int l15 = lane & 15, lhi = lane >> 4;
  const int bm = blockIdx.x * 64, bn = blockIdx.y * 128;
  const int srow = tid >> 2, scol = (tid & 3) * 8;
  const u16* ga = A + (size_t)(bm + srow) * K + scol;
  const u16* gb = Bt + (size_t)(bn + srow) * K + scol;
  f32x4 acc[2][4] = {};
  const int aoff = (wr * 32 + l15) * BK + lhi * 8;
  const int boff = (wc * 64 + l15) * BK + lhi * 8;
  const int NT = K / BK;
#pragma unroll
  for (int p = 0; p < 2; p++) {
    GLL16(ga + p * BK, &As[p][tid * 8]);
    GLL16(gb + p * BK, &Bs[p][tid * 8]);
    GLL16(gb + (size_t)64 * K + p * BK, &Bs[p][2048 + tid * 8]);
  }
  int cur = 0, nxt = 2;
  for (int k = 0; k < NT; ++k) {
    if (k + 1 < NT) asm volatile("s_waitcnt vmcnt(3)" ::: "memory");
    else            asm volatile("s_waitcnt vmcnt(0)" ::: "memory");
    __builtin_amdgcn_s_barrier();
    if (k + 2 < NT) {
      const int k2 = (k + 2) * BK;
      GLL16(ga + k2, &As[nxt][tid * 8]);
      GLL16(gb + k2, &Bs[nxt][tid * 8]);
      GLL16(gb + (size_t)64 * K + k2, &Bs[nxt][2048 + tid * 8]);
    }
    bf16x8 af[2], bfr[4];
#pragma unroll
    for (int i = 0; i < 2; i++) af[i] = *(const bf16x8*)&As[cur][aoff + i * 16 * BK];
#pragma unroll
    for (int j = 0; j < 4; j++) bfr[j] = *(const bf16x8*)&Bs[cur][boff + j * 16 * BK];
#pragma unroll
    for (int i = 0; i < 2; i++)
#pragma unroll
      for (int j = 0; j < 4; j++)
        acc[i][j] = __builtin_amdgcn_mfma_f32_16x16x32_bf16(af[i], bfr[j], acc[i][j], 0, 0, 0);
    cur = (cur == 2) ? 0 : cur + 1;
    nxt = (nxt == 2) ? 0 : nxt + 1;
  }
  const int crow0 = bm + wr * 32 + lhi * 4, ccol0 = bn + wc * 64 + l15;
#pragma unroll
  for (int i = 0; i < 2; i++)
#pragma unroll
    for (int j = 0; j < 4; j++)
#pragma unroll
      for (int r = 0; r < 4; r++)
        C[(size_t)(crow0 + i * 16 + r) * N + ccol0 + j * 16] = acc[i][j][r];
}

// ---------- causal flash attention v7 ----------
// v5 + write-early staging with 2-deep prefetch (A/B reg ping-pong) +
// defer-max THR=8 (exact-division cancels the scale; P <= 2^8 in bf16).
__global__ __launch_bounds__(256, 4) void k_attn(
    const u16* __restrict__ q_bf, const u16* __restrict__ k_bf,
    const u16* __restrict__ vT_bf, u16* __restrict__ att_bf) {
  __shared__ __align__(16) char lds[40960];
  const int bid = blockIdx.x;
  const int g = bid >> 5, g0 = g & 7, gs = g >> 3;
  const int qb = (gs == 0) ? (31 - g0) : (gs == 1) ? g0 : (gs == 2) ? (23 - g0) : (8 + g0);
  const int hb = bid & 31;
  const int h = hb & 15, b = hb >> 4;
  const int kvh = h >> 2;
  const int tid = threadIdx.x, lane = tid & 63, w = tid >> 6;
  const int l15 = lane & 15, lhi = lane >> 4;
  const u16* Qg = q_bf + ((size_t)((b * H_C + h) * T_C) + qb * 64) * 64;
  const u16* Kg = k_bf + ((size_t)((b * KV_C + kvh) * T_C)) * 64;
  const u16* Vg = vT_bf + (size_t)(b * KV_C + kvh) * 64 * T_C;  // [64][T]

  bf16x8 qf[2];
  const int qrow = w * 16 + l15;
#pragma unroll
  for (int kc = 0; kc < 2; kc++)
    qf[kc] = *(const bf16x8*)&Qg[(size_t)qrow * 64 + kc * 32 + lhi * 8];

  f32x4 o[4] = {};
  float m = -1e30f, lsum = 0.f;

  const int nt = qb + 1;
  const int r0 = tid >> 3, j0 = tid & 7;
  const int r1 = r0 + 32;
  const int wb0 = r0 * 128 + ((j0 * 16) ^ ((r0 & 7) << 4));
  const int wb1 = r1 * 128 + ((j0 * 16) ^ ((r1 & 7) << 4));
  char* psb = lds + 0x8000 + w * 0x800;
  const int psw = (l15 & 7) << 4;

  // prologue: tile 0 -> regs A -> buf0; tile 1 -> regs B
  bf16x8 krA0, krA1, vrA0, vrA1, krB0, krB1, vrB0, vrB1;
  krA0 = *(const bf16x8*)&Kg[(size_t)r0 * 64 + j0 * 8];
  krA1 = *(const bf16x8*)&Kg[(size_t)r1 * 64 + j0 * 8];
  vrA0 = *(const bf16x8*)&Vg[(size_t)r0 * T_C + j0 * 8];
  vrA1 = *(const bf16x8*)&Vg[(size_t)r1 * T_C + j0 * 8];
  *(bf16x8*)(lds + wb0) = krA0;
  *(bf16x8*)(lds + wb1) = krA1;
  *(bf16x8*)(lds + 0x4000 + wb0) = vrA0;
  *(bf16x8*)(lds + 0x4000 + wb1) = vrA1;
  if (nt > 1) {
    krB0 = *(const bf16x8*)&Kg[(size_t)(64 + r0) * 64 + j0 * 8];
    krB1 = *(const bf16x8*)&Kg[(size_t)(64 + r1) * 64 + j0 * 8];
    vrB0 = *(const bf16x8*)&Vg[(size_t)r0 * T_C + 64 + j0 * 8];
    vrB1 = *(const bf16x8*)&Vg[(size_t)r1 * T_C + 64 + j0 * 8];
  }
  __syncthreads();

  for (int it = 0; it < nt; ++it) {
    const int coff = (it & 1) * 0x2000;
    const int noff = coff ^ 0x2000;
    // ---- write-early: stage tile it+1 into the free buffer; issue it+2 ----
    if ((it & 1) == 0) {
      if (it + 1 < nt) {
        *(bf16x8*)(lds + noff + wb0) = krB0;
        *(bf16x8*)(lds + noff + wb1) = krB1;
        *(bf16x8*)(lds + 0x4000 + noff + wb0) = vrB0;
        *(bf16x8*)(lds + 0x4000 + noff + wb1) = vrB1;
      }
      if (it + 2 < nt) {
        const int t2 = (it + 2) * 64;
        krA0 = *(const bf16x8*)&Kg[(size_t)(t2 + r0) * 64 + j0 * 8];
        krA1 = *(const bf16x8*)&Kg[(size_t)(t2 + r1) * 64 + j0 * 8];
        vrA0 = *(const bf16x8*)&Vg[(size_t)r0 * T_C + t2 + j0 * 8];
        vrA1 = *(const bf16x8*)&Vg[(size_t)r1 * T_C + t2 + j0 * 8];
      }
    } else {
      if (it + 1 < nt) {
        *(bf16x8*)(lds + noff + wb0) = krA0;
        *(bf16x8*)(lds + noff + wb1) = krA1;
        *(bf16x8*)(lds + 0x4000 + noff + wb0) = vrA0;
        *(bf16x8*)(lds + 0x4000 + noff + wb1) = vrA1;
      }
      if (it + 2 < nt) {
        const int t2 = (it + 2) * 64;
        krB0 = *(const bf16x8*)&Kg[(size_t)(t2 + r0) * 64 + j0 * 8];
        krB1 = *(const bf16x8*)&Kg[(size_t)(t2 + r1) * 64 + j0 * 8];
        vrB0 = *(const bf16x8*)&Vg[(size_t)r0 * T_C + t2 + j0 * 8];
        vrB1 = *(const bf16x8*)&Vg[(size_t)r1 * T_C + t2 + j0 * 8];
      }
    }
    // ---- S^T = K Q^T (swapped operands; q = l15, key = nf*16+lhi*4+r) ----
    bf16x8 kf[4][2];
#pragma unroll
    for (int nf = 0; nf < 4; nf++)
#pragma unroll
      for (int kc = 0; kc < 2; kc++) {
        const int row = nf * 16 + l15;
        kf[nf][kc] = *(const bf16x8*)(lds + coff + row * 128 +
                                      ((kc * 64 + lhi * 16) ^ ((l15 & 7) << 4)));
      }
    f32x4 s[4] = {};
    __builtin_amdgcn_s_setprio(1);
#pragma unroll
    for (int nf = 0; nf < 4; nf++)
#pragma unroll
      for (int kc = 0; kc < 2; kc++)
        s[nf] = __builtin_amdgcn_mfma_f32_16x16x32_bf16(kf[nf][kc], qf[kc], s[nf], 0, 0, 0);
    __builtin_amdgcn_s_setprio(0);
    // ---- causal mask on diagonal tile: key > q ----
    if (it == nt - 1) {
      const int qg = w * 16 + l15;
#pragma unroll
      for (int nf = 0; nf < 4; nf++) {
        const int kb2 = nf * 16 + lhi * 4;
#pragma unroll
        for (int r = 0; r < 4; r++)
          if (kb2 + r > qg) s[nf][r] = -1e30f;
      }
    }
    // ---- online softmax with defer-max (THR=8 in exp2 domain) ----
    float a0 = fmaxf(fmaxf(s[0][0], s[0][1]), fmaxf(s[0][2], s[0][3]));
    float a1 = fmaxf(fmaxf(s[1][0], s[1][1]), fmaxf(s[1][2], s[1][3]));
    float a2 = fmaxf(fmaxf(s[2][0], s[2][1]), fmaxf(s[2][2], s[2][3]));
    float a3 = fmaxf(fmaxf(s[3][0], s[3][1]), fmaxf(s[3][2], s[3][3]));
    float tmax = fmaxf(fmaxf(a0, a1), fmaxf(a2, a3));
    tmax = fmaxf(tmax, __shfl_xor(tmax, 16, 64));
    tmax = fmaxf(tmax, __shfl_xor(tmax, 32, 64));
    if (__any(tmax > m + 8.0f)) {
      float mn = fmaxf(m, tmax);
      float alpha = __builtin_exp2f(m - mn);
      m = mn;
      lsum *= alpha;
      float ar[4];
#pragma unroll
      for (int r = 0; r < 4; r++) ar[r] = __shfl(alpha, lhi * 4 + r, 64);
#pragma unroll
      for (int nf = 0; nf < 4; nf++)
#pragma unroll
        for (int r = 0; r < 4; r++) o[nf][r] *= ar[r];
    }
    // ---- P = exp2(S - m), pack bf16 pairs, 8x ds_write_b32 ----
#pragma unroll
    for (int nf = 0; nf < 4; nf++) {
      float p0 = __builtin_exp2f(s[nf][0] - m);
      float p1 = __builtin_exp2f(s[nf][1] - m);
      float p2 = __builtin_exp2f(s[nf][2] - m);
      float p3 = __builtin_exp2f(s[nf][3] - m);
      lsum += (p0 + p1) + (p2 + p3);
      unsigned lo = cvtpk(p0, p1), hi = cvtpk(p2, p3);
      const int pb = ((nf * 32 + lhi * 8) ^ psw) + l15 * 128;
      *(unsigned*)(psb + pb) = lo;
      *(unsigned*)(psb + pb + 4) = hi;
    }
    asm volatile("s_waitcnt lgkmcnt(0)" ::: "memory");
    __builtin_amdgcn_sched_barrier(0);
    // ---- O += P V ----
    __builtin_amdgcn_s_setprio(1);
#pragma unroll
    for (int kc = 0; kc < 2; kc++) {
      bf16x8 pa = *(const bf16x8*)(psb + l15 * 128 +
                                   ((kc * 64 + lhi * 16) ^ ((l15 & 7) << 4)));
#pragma unroll
      for (int nf = 0; nf < 4; nf++) {
        bf16x8 vf = *(const bf16x8*)(lds + 0x4000 + coff + (nf * 16 + l15) * 128 +
                                     ((kc * 64 + lhi * 16) ^ ((l15 & 7) << 4)));
        o[nf] = __builtin_amdgcn_mfma_f32_16x16x32_bf16(pa, vf, o[nf], 0, 0, 0);
      }
    }
    __builtin_amdgcn_s_setprio(0);
    __syncthreads();
  }
  // ---- epilogue: reduce lsum over lhi, redistribute inv to O rows ----
  lsum += __shfl_xor(lsum, 16, 64);
  lsum += __shfl_xor(lsum, 32, 64);
  float inv = 1.0f / lsum;
  float invr[4];
#pragma unroll
  for (int r = 0; r < 4; r++) invr[r] = __shfl(inv, lhi * 4 + r, 64);
  const int trow = qb * 64 + w * 16 + lhi * 4;
  const size_t obase = ((size_t)(b * T_C) + trow) * 1024 + h * 64;
#pragma unroll
  for (int nf = 0; nf < 4; nf++)
#pragma unroll
    for (int r = 0; r < 4; r++)
      att_bf[obase + (size_t)r * 1024 + nf * 16 + l15] = f2bf(o[nf][r] * invr[r]);
}

extern "C" void kernel_launch(void* const* d_in, const int* in_sizes, int n_in,
                              void* d_out, int out_size, void* d_ws, size_t ws_size,
                              hipStream_t stream) {
  const float* x  = (const float*)d_in[0];
  const float* wq = (const float*)d_in[2];
  const float* wk = (const float*)d_in[3];
  const float* wv = (const float*)d_in[4];
  const float* wo = (const float*)d_in[5];
  float* out = (float*)d_out;

  char* ws = (char*)d_ws;
  u16*   xb    = (u16*)(ws);                          //  8 MiB
  u16*   wqkvT = (u16*)(ws + (8ull  << 20));          //  3 MiB
  u16*   woT   = (u16*)(ws + (11ull << 20));          //  2 MiB
  u16*   vT_bf = (u16*)(ws + (13ull << 20));          //  2 MiB
  f32x2* tab   = (f32x2*)(ws + (15ull << 20));        // 512 KiB
  u16*   q_bf  = (u16*)(ws + (37ull << 20));          //  8 MiB
  u16*   k_bf  = (u16*)(ws + (45ull << 20));          //  2 MiB
  u16*   attb  = (u16*)(ws + (49ull << 20));          //  8 MiB

  k_prep<<<6912, 256, 0, stream>>>(x, xb, wq, wk, wv, wo, wqkvT, woT, tab);
  k_gemm_qkv<<<dim3(64, 12), 256, 0, stream>>>(xb, wqkvT, tab, q_bf, k_bf, vT_bf);
  k_attn<<<1024, 256, 0, stream>>>(q_bf, k_bf, vT_bf, attb);
  k_gemm_bt<<<dim3(64, 8), 256, 0, stream>>>(attb, woT, out, 4096, 1024, 1024);
}

// Round 15
// 103.639 us; speedup vs baseline: 1.0202x; 1.0202x over previous
//
#include <hip/hip_runtime.h>
#include <cstdint>

typedef unsigned short u16;
typedef __attribute__((ext_vector_type(2))) float f32x2;
typedef __attribute__((ext_vector_type(4))) float f32x4;
typedef __attribute__((ext_vector_type(8))) short bf16x8;
typedef __attribute__((ext_vector_type(4))) u16 u16x4;
typedef __attribute__((ext_vector_type(4))) unsigned u32x4;

#define B_C 2
#define T_C 2048
#define H_C 16
#define KV_C 4

__device__ __forceinline__ u16 f2bf(float f) {
  unsigned u = __builtin_bit_cast(unsigned, f);
  u = (u + 0x7fffu + ((u >> 16) & 1u)) >> 16;
  return (u16)u;
}

__device__ __forceinline__ unsigned cvtpk(float a, float b) {
  unsigned r;
  asm("v_cvt_pk_bf16_f32 %0, %1, %2" : "=v"(r) : "v"(a), "v"(b));
  return r;
}

#define GLL16(src, dst)                                                     \
  __builtin_amdgcn_global_load_lds(                                         \
      (__attribute__((address_space(1))) void*)(src),                       \
      (__attribute__((address_space(3))) void*)(dst), 16, 0, 0)

// ---------- fused prep: x->bf16, 4 weight transposes, cos/sin table ----------
__global__ void k_prep(const float* __restrict__ x, u16* __restrict__ xb,
                       const float* __restrict__ wq, const float* __restrict__ wk,
                       const float* __restrict__ wv, const float* __restrict__ wo,
                       u16* __restrict__ wqkvT, u16* __restrict__ woT,
                       f32x2* __restrict__ tab) {
  __shared__ float t[32][33];
  const int bid = blockIdx.x, tid = threadIdx.x;
  if (bid < 4096) {
    int i = bid * 256 + tid;
    f32x4 v = *(const f32x4*)(x + (size_t)i * 4);
    u16x4 o;
    o[0] = f2bf(v[0]); o[1] = f2bf(v[1]); o[2] = f2bf(v[2]); o[3] = f2bf(v[3]);
    *(u16x4*)(xb + (size_t)i * 4) = o;
  } else if (bid < 6656) {
    const float* in; u16* out; int N, lb;
    if (bid < 5120)      { in = wq; out = wqkvT;               N = 1024; lb = bid - 4096; }
    else if (bid < 5376) { in = wk; out = wqkvT + 1024 * 1024; N = 256;  lb = bid - 5120; }
    else if (bid < 5632) { in = wv; out = wqkvT + 1280 * 1024; N = 256;  lb = bid - 5376; }
    else                 { in = wo; out = woT;                 N = 1024; lb = bid - 5632; }
    const int kb = (lb & 31) * 32, nb = (lb >> 5) * 32;
    const int tx = tid & 31, ty = tid >> 5;
#pragma unroll
    for (int i = 0; i < 32; i += 8) t[ty + i][tx] = in[(size_t)(kb + ty + i) * N + nb + tx];
    __syncthreads();
#pragma unroll
    for (int i = 0; i < 32; i += 8) out[(size_t)(nb + ty + i) * 1024 + kb + tx] = f2bf(t[tx][ty + i]);
  } else {
    int idx = (bid - 6656) * 256 + tid;  // t*32 + i
    int i = idx & 31, tt = idx >> 5;
    float ang = (float)tt * exp2f(-(float)(2 * i) * (13.28771237954945f / 64.0f));
    float sn, cs; sincosf(ang, &sn, &cs);
    f32x2 v; v.x = cs; v.y = sn;
    tab[idx] = v;
  }
}

// ---------- GEMM1: 64x128 tile, 3-buf counted-vmcnt, fused RoPE epilogue ----------
__global__ __launch_bounds__(256, 3) void k_gemm_qkv(
    const u16* __restrict__ A, const u16* __restrict__ Bt,
    const f32x2* __restrict__ tab,
    u16* __restrict__ qb_, u16* __restrict__ kb_, u16* __restrict__ vT_) {
  constexpr int BK = 32, K = 1024, NT = K / BK;
  __shared__ u16 As[3][64 * BK];
  __shared__ u16 Bs[3][128 * BK];
  const int tid = threadIdx.x;
  const int lane = tid & 63, wid = tid >> 6;
  const int wr = wid >> 1, wc = wid & 1;
  const int l15 = lane & 15, lhi = lane >> 4;
  const int bm = blockIdx.x * 64, bn = blockIdx.y * 128;
  const int srow = tid >> 2, scol = (tid & 3) * 8;
  const u16* ga = A + (size_t)(bm + srow) * K + scol;
  const u16* gb = Bt + (size_t)(bn + srow) * K + scol;
  f32x4 acc[2][4] = {};
  const int aoff = (wr * 32 + l15) * BK + lhi * 8;
  const int boff = (wc * 64 + l15) * BK + lhi * 8;
#pragma unroll
  for (int p = 0; p < 2; p++) {
    GLL16(ga + p * BK, &As[p][tid * 8]);
    GLL16(gb + p * BK, &Bs[p][tid * 8]);
    GLL16(gb + (size_t)64 * K + p * BK, &Bs[p][2048 + tid * 8]);
  }
  int cur = 0, nxt = 2;
  for (int k = 0; k < NT; ++k) {
    if (k + 1 < NT) asm volatile("s_waitcnt vmcnt(3)" ::: "memory");
    else            asm volatile("s_waitcnt vmcnt(0)" ::: "memory");
    __builtin_amdgcn_s_barrier();
    if (k + 2 < NT) {
      const int k2 = (k + 2) * BK;
      GLL16(ga + k2, &As[nxt][tid * 8]);
      GLL16(gb + k2, &Bs[nxt][tid * 8]);
      GLL16(gb + (size_t)64 * K + k2, &Bs[nxt][2048 + tid * 8]);
    }
    bf16x8 af[2], bfr[4];
#pragma unroll
    for (int i = 0; i < 2; i++) af[i] = *(const bf16x8*)&As[cur][aoff + i * 16 * BK];
#pragma unroll
    for (int j = 0; j < 4; j++) bfr[j] = *(const bf16x8*)&Bs[cur][boff + j * 16 * BK];
#pragma unroll
    for (int i = 0; i < 2; i++)
#pragma unroll
      for (int j = 0; j < 4; j++)
        acc[i][j] = __builtin_amdgcn_mfma_f32_16x16x32_bf16(af[i], bfr[j], acc[i][j], 0, 0, 0);
    cur = (cur == 2) ? 0 : cur + 1;
    nxt = (nxt == 2) ? 0 : nxt + 1;
  }
  // ---- fused epilogue ----
  const int crow0 = bm + wr * 32 + lhi * 4;
  const int bsel = (blockIdx.x >= 32) ? 1 : 0;
  const int hg = (bn >> 6) + wc;
  if (blockIdx.y >= 10) {
    u16* dst = vT_ + ((size_t)(bsel * KV_C + (hg - 20)) * 64) * T_C;
#pragma unroll
    for (int j = 0; j < 4; j++) {
      const int d = l15 + j * 16;
#pragma unroll
      for (int i = 0; i < 2; i++) {
        const int t2 = (crow0 + i * 16) & 2047;
        u16x4 pk;
#pragma unroll
        for (int r = 0; r < 4; r++) pk[r] = f2bf(acc[i][j][r]);
        *(u16x4*)&dst[(size_t)d * T_C + t2] = pk;
      }
    }
  } else {
    const bool isq = (blockIdx.y < 8);
    u16* dst = isq ? (qb_ + ((size_t)(bsel * H_C + hg) * T_C) * 64)
                   : (kb_ + ((size_t)(bsel * KV_C + (hg - 16)) * T_C) * 64);
    const float sc = isq ? (0.125f * 1.4426950408889634f) : 1.0f;
    const int par = l15 & 1;
#pragma unroll
    for (int j = 0; j < 4; j++) {
      const int d = l15 + j * 16;
      const int ir = (l15 >> 1) + j * 8;
#pragma unroll
      for (int i = 0; i < 2; i++)
#pragma unroll
        for (int r = 0; r < 4; r++) {
          const int t2 = (crow0 + i * 16 + r) & 2047;
          float v = acc[i][j][r];
          float p = __shfl_xor(v, 1, 64);
          f32x2 cs = tab[t2 * 32 + ir];
          float sgn = par ? cs.y : -cs.y;
          dst[(size_t)t2 * 64 + d] = f2bf((v * cs.x + p * sgn) * sc);
        }
    }
  }
}

// ---------- GEMM2: 64x128 tile, 3-buf counted-vmcnt ----------
__global__ __launch_bounds__(256, 3) void k_gemm_bt(
    const u16* __restrict__ A, const u16* __restrict__ Bt, float* __restrict__ C,
    int M, int N, int K) {
  constexpr int BK = 32;
  __shared__ u16 As[3][64 * BK];
  __shared__ u16 Bs[3][128 * BK];
  const int tid = threadIdx.x;
  const int lane = tid & 63, wid = tid >> 6;
  const int wr = wid >> 1, wc = wid & 1;
  const int l15 = lane & 15, lhi = lane >> 4;
  const int bm = blockIdx.x * 64, bn = blockIdx.y * 128;
  const int srow = tid >> 2, scol = (tid & 3) * 8;
  const u16* ga = A + (size_t)(bm + srow) * K + scol;
  const u16* gb = Bt + (size_t)(bn + srow) * K + scol;
  f32x4 acc[2][4] = {};
  const int aoff = (wr * 32 + l15) * BK + lhi * 8;
  const int boff = (wc * 64 + l15) * BK + lhi * 8;
  const int NT = K / BK;
#pragma unroll
  for (int p = 0; p < 2; p++) {
    GLL16(ga + p * BK, &As[p][tid * 8]);
    GLL16(gb + p * BK, &Bs[p][tid * 8]);
    GLL16(gb + (size_t)64 * K + p * BK, &Bs[p][2048 + tid * 8]);
  }
  int cur = 0, nxt = 2;
  for (int k = 0; k < NT; ++k) {
    if (k + 1 < NT) asm volatile("s_waitcnt vmcnt(3)" ::: "memory");
    else            asm volatile("s_waitcnt vmcnt(0)" ::: "memory");
    __builtin_amdgcn_s_barrier();
    if (k + 2 < NT) {
      const int k2 = (k + 2) * BK;
      GLL16(ga + k2, &As[nxt][tid * 8]);
      GLL16(gb + k2, &Bs[nxt][tid * 8]);
      GLL16(gb + (size_t)64 * K + k2, &Bs[nxt][2048 + tid * 8]);
    }
    bf16x8 af[2], bfr[4];
#pragma unroll
    for (int i = 0; i < 2; i++) af[i] = *(const bf16x8*)&As[cur][aoff + i * 16 * BK];
#pragma unroll
    for (int j = 0; j < 4; j++) bfr[j] = *(const bf16x8*)&Bs[cur][boff + j * 16 * BK];
#pragma unroll
    for (int i = 0; i < 2; i++)
#pragma unroll
      for (int j = 0; j < 4; j++)
        acc[i][j] = __builtin_amdgcn_mfma_f32_16x16x32_bf16(af[i], bfr[j], acc[i][j], 0, 0, 0);
    cur = (cur == 2) ? 0 : cur + 1;
    nxt = (nxt == 2) ? 0 : nxt + 1;
  }
  const int crow0 = bm + wr * 32 + lhi * 4, ccol0 = bn + wc * 64 + l15;
#pragma unroll
  for (int i = 0; i < 2; i++)
#pragma unroll
    for (int j = 0; j < 4; j++)
#pragma unroll
      for (int r = 0; r < 4; r++)
        C[(size_t)(crow0 + i * 16 + r) * N + ccol0 + j * 16] = acc[i][j][r];
}

// ---------- causal flash attention v8 ----------
// = v5 (R13-proven) with ONE change: P stays in registers. The 8 bank-
// conflicted ds_write_b32 + lgkmcnt(0) drain + 2 ds_read_b128 are replaced
// by 16 shfl + 8 selects on cvtpk-packed words (value-identical). P LDS gone.
__global__ __launch_bounds__(256, 4) void k_attn(
    const u16* __restrict__ q_bf, const u16* __restrict__ k_bf,
    const u16* __restrict__ vT_bf, u16* __restrict__ att_bf) {
  __shared__ __align__(16) char lds[32768];
  const int bid = blockIdx.x;
  const int g = bid >> 5, g0 = g & 7, gs = g >> 3;
  const int qb = (gs == 0) ? (31 - g0) : (gs == 1) ? g0 : (gs == 2) ? (23 - g0) : (8 + g0);
  const int hb = bid & 31;
  const int h = hb & 15, b = hb >> 4;
  const int kvh = h >> 2;
  const int tid = threadIdx.x, lane = tid & 63, w = tid >> 6;
  const int l15 = lane & 15, lhi = lane >> 4;
  const u16* Qg = q_bf + ((size_t)((b * H_C + h) * T_C) + qb * 64) * 64;
  const u16* Kg = k_bf + ((size_t)((b * KV_C + kvh) * T_C)) * 64;
  const u16* Vg = vT_bf + (size_t)(b * KV_C + kvh) * 64 * T_C;  // [64][T]

  bf16x8 qf[2];
  const int qrow = w * 16 + l15;
#pragma unroll
  for (int kc = 0; kc < 2; kc++)
    qf[kc] = *(const bf16x8*)&Qg[(size_t)qrow * 64 + kc * 32 + lhi * 8];

  f32x4 o[4] = {};
  float m = -1e30f, lsum = 0.f;

  const int nt = qb + 1;
  const int r0 = tid >> 3, j0 = tid & 7;
  const int r1 = r0 + 32;
  const int wb0 = r0 * 128 + ((j0 * 16) ^ ((r0 & 7) << 4));
  const int wb1 = r1 * 128 + ((j0 * 16) ^ ((r1 & 7) << 4));

  bf16x8 kr0, kr1, vr0, vr1;
  kr0 = *(const bf16x8*)&Kg[(size_t)r0 * 64 + j0 * 8];
  kr1 = *(const bf16x8*)&Kg[(size_t)r1 * 64 + j0 * 8];
  vr0 = *(const bf16x8*)&Vg[(size_t)r0 * T_C + j0 * 8];
  vr1 = *(const bf16x8*)&Vg[(size_t)r1 * T_C + j0 * 8];
  *(bf16x8*)(lds + wb0) = kr0;
  *(bf16x8*)(lds + wb1) = kr1;
  *(bf16x8*)(lds + 0x4000 + wb0) = vr0;
  *(bf16x8*)(lds + 0x4000 + wb1) = vr1;
  __syncthreads();

  for (int it = 0; it < nt; ++it) {
    const int t0 = it * 64;
    const int coff = (it & 1) * 0x2000;
    if (it + 1 < nt) {
      const int t1 = t0 + 64;
      kr0 = *(const bf16x8*)&Kg[(size_t)(t1 + r0) * 64 + j0 * 8];
      kr1 = *(const bf16x8*)&Kg[(size_t)(t1 + r1) * 64 + j0 * 8];
      vr0 = *(const bf16x8*)&Vg[(size_t)r0 * T_C + t1 + j0 * 8];
      vr1 = *(const bf16x8*)&Vg[(size_t)r1 * T_C + t1 + j0 * 8];
    }
    // ---- S^T = K Q^T (swapped operands; q = l15, key = nf*16+lhi*4+r) ----
    bf16x8 kf[4][2];
#pragma unroll
    for (int nf = 0; nf < 4; nf++)
#pragma unroll
      for (int kc = 0; kc < 2; kc++) {
        const int row = nf * 16 + l15;
        kf[nf][kc] = *(const bf16x8*)(lds + coff + row * 128 +
                                      ((kc * 64 + lhi * 16) ^ ((l15 & 7) << 4)));
      }
    f32x4 s[4] = {};
    __builtin_amdgcn_s_setprio(1);
#pragma unroll
    for (int nf = 0; nf < 4; nf++)
#pragma unroll
      for (int kc = 0; kc < 2; kc++)
        s[nf] = __builtin_amdgcn_mfma_f32_16x16x32_bf16(kf[nf][kc], qf[kc], s[nf], 0, 0, 0);
    __builtin_amdgcn_s_setprio(0);
    // ---- causal mask on diagonal tile: key > q ----
    if (it == nt - 1) {
      const int qg = w * 16 + l15;
#pragma unroll
      for (int nf = 0; nf < 4; nf++) {
        const int kb2 = nf * 16 + lhi * 4;
#pragma unroll
        for (int r = 0; r < 4; r++)
          if (kb2 + r > qg) s[nf][r] = -1e30f;
      }
    }
    // ---- online softmax: lane owns q-row; 2-shfl reduce over lhi ----
    float a0 = fmaxf(fmaxf(s[0][0], s[0][1]), fmaxf(s[0][2], s[0][3]));
    float a1 = fmaxf(fmaxf(s[1][0], s[1][1]), fmaxf(s[1][2], s[1][3]));
    float a2 = fmaxf(fmaxf(s[2][0], s[2][1]), fmaxf(s[2][2], s[2][3]));
    float a3 = fmaxf(fmaxf(s[3][0], s[3][1]), fmaxf(s[3][2], s[3][3]));
    float tmax = fmaxf(fmaxf(a0, a1), fmaxf(a2, a3));
    tmax = fmaxf(tmax, __shfl_xor(tmax, 16, 64));
    tmax = fmaxf(tmax, __shfl_xor(tmax, 32, 64));
    if (__any(tmax > m)) {
      float mn = fmaxf(m, tmax);
      float alpha = __builtin_exp2f(m - mn);
      m = mn;
      lsum *= alpha;
      float ar[4];
#pragma unroll
      for (int r = 0; r < 4; r++) ar[r] = __shfl(alpha, lhi * 4 + r, 64);
#pragma unroll
      for (int nf = 0; nf < 4; nf++)
#pragma unroll
        for (int r = 0; r < 4; r++) o[nf][r] *= ar[r];
    }
    // ---- P = exp2(S - m), pack to bf16 pairs (stays in registers) ----
    unsigned pk[4][2];
#pragma unroll
    for (int nf = 0; nf < 4; nf++) {
      float p0 = __builtin_exp2f(s[nf][0] - m);
      float p1 = __builtin_exp2f(s[nf][1] - m);
      float p2 = __builtin_exp2f(s[nf][2] - m);
      float p3 = __builtin_exp2f(s[nf][3] - m);
      lsum += (p0 + p1) + (p2 + p3);
      pk[nf][0] = cvtpk(p0, p1);
      pk[nf][1] = cvtpk(p2, p3);
    }
    // ---- redistribute P to PV A-fragment layout via shfl (no LDS) ----
    // target (l15,lhi) keys kc*32+lhi*8+j: src lanes l15+32*(lhi&1)+{0,16},
    // word pk[2kc+(lhi>>1)][j>>2]
    const int srcA = l15 + ((lhi & 1) << 5);
    const bool hi2 = (lhi & 2);
    // ---- O += P V ----
    __builtin_amdgcn_s_setprio(1);
#pragma unroll
    for (int kc = 0; kc < 2; kc++) {
      unsigned va0 = (unsigned)__shfl((int)pk[2 * kc][0], srcA, 64);
      unsigned vb0 = (unsigned)__shfl((int)pk[2 * kc + 1][0], srcA, 64);
      unsigned va1 = (unsigned)__shfl((int)pk[2 * kc][1], srcA, 64);
      unsigned vb1 = (unsigned)__shfl((int)pk[2 * kc + 1][1], srcA, 64);
      unsigned va2 = (unsigned)__shfl((int)pk[2 * kc][0], srcA + 16, 64);
      unsigned vb2 = (unsigned)__shfl((int)pk[2 * kc + 1][0], srcA + 16, 64);
      unsigned va3 = (unsigned)__shfl((int)pk[2 * kc][1], srcA + 16, 64);
      unsigned vb3 = (unsigned)__shfl((int)pk[2 * kc + 1][1], srcA + 16, 64);
      u32x4 paw;
      paw[0] = hi2 ? vb0 : va0;
      paw[1] = hi2 ? vb1 : va1;
      paw[2] = hi2 ? vb2 : va2;
      paw[3] = hi2 ? vb3 : va3;
      bf16x8 pa = __builtin_bit_cast(bf16x8, paw);
#pragma unroll
      for (int nf = 0; nf < 4; nf++) {
        bf16x8 vf = *(const bf16x8*)(lds + 0x4000 + coff + (nf * 16 + l15) * 128 +
                                     ((kc * 64 + lhi * 16) ^ ((l15 & 7) << 4)));
        o[nf] = __builtin_amdgcn_mfma_f32_16x16x32_bf16(pa, vf, o[nf], 0, 0, 0);
      }
    }
    __builtin_amdgcn_s_setprio(0);
    if (it + 1 < nt) {
      const int noff = ((it + 1) & 1) * 0x2000;
      *(bf16x8*)(lds + noff + wb0) = kr0;
      *(bf16x8*)(lds + noff + wb1) = kr1;
      *(bf16x8*)(lds + 0x4000 + noff + wb0) = vr0;
      *(bf16x8*)(lds + 0x4000 + noff + wb1) = vr1;
    }
    __syncthreads();
  }
  // ---- epilogue: reduce lsum over lhi, redistribute inv to O rows ----
  lsum += __shfl_xor(lsum, 16, 64);
  lsum += __shfl_xor(lsum, 32, 64);
  float inv = 1.0f / lsum;
  float invr[4];
#pragma unroll
  for (int r = 0; r < 4; r++) invr[r] = __shfl(inv, lhi * 4 + r, 64);
  const int trow = qb * 64 + w * 16 + lhi * 4;
  const size_t obase = ((size_t)(b * T_C) + trow) * 1024 + h * 64;
#pragma unroll
  for (int nf = 0; nf < 4; nf++)
#pragma unroll
    for (int r = 0; r < 4; r++)
      att_bf[obase + (size_t)r * 1024 + nf * 16 + l15] = f2bf(o[nf][r] * invr[r]);
}

extern "C" void kernel_launch(void* const* d_in, const int* in_sizes, int n_in,
                              void* d_out, int out_size, void* d_ws, size_t ws_size,
                              hipStream_t stream) {
  const float* x  = (const float*)d_in[0];
  const float* wq = (const float*)d_in[2];
  const float* wk = (const float*)d_in[3];
  const float* wv = (const float*)d_in[4];
  const float* wo = (const float*)d_in[5];
  float* out = (float*)d_out;

  char* ws = (char*)d_ws;
  u16*   xb    = (u16*)(ws);                          //  8 MiB
  u16*   wqkvT = (u16*)(ws + (8ull  << 20));          //  3 MiB
  u16*   woT   = (u16*)(ws + (11ull << 20));          //  2 MiB
  u16*   vT_bf = (u16*)(ws + (13ull << 20));          //  2 MiB
  f32x2* tab   = (f32x2*)(ws + (15ull << 20));        // 512 KiB
  u16*   q_bf  = (u16*)(ws + (37ull << 20));          //  8 MiB
  u16*   k_bf  = (u16*)(ws + (45ull << 20));          //  2 MiB
  u16*   attb  = (u16*)(ws + (49ull << 20));          //  8 MiB

  k_prep<<<6912, 256, 0, stream>>>(x, xb, wq, wk, wv, wo, wqkvT, woT, tab);
  k_gemm_qkv<<<dim3(64, 12), 256, 0, stream>>>(xb, wqkvT, tab, q_bf, k_bf, vT_bf);
  k_attn<<<1024, 256, 0, stream>>>(q_bf, k_bf, vT_bf, attb);
  k_gemm_bt<<<dim3(64, 8), 256, 0, stream>>>(attb, woT, out, 4096, 1024, 1024);
}

// Round 16
// 97.701 us; speedup vs baseline: 1.0822x; 1.0608x over previous
//
#include <hip/hip_runtime.h>
#include <cstdint>

typedef unsigned short u16;
typedef __attribute__((ext_vector_type(2))) float f32x2;
typedef __attribute__((ext_vector_type(4))) float f32x4;
typedef __attribute__((ext_vector_type(8))) short bf16x8;
typedef __attribute__((ext_vector_type(4))) u16 u16x4;

#define B_C 2
#define T_C 2048
#define H_C 16
#define KV_C 4

__device__ __forceinline__ u16 f2bf(float f) {
  unsigned u = __builtin_bit_cast(unsigned, f);
  u = (u + 0x7fffu + ((u >> 16) & 1u)) >> 16;
  return (u16)u;
}

__device__ __forceinline__ unsigned cvtpk(float a, float b) {
  unsigned r;
  asm("v_cvt_pk_bf16_f32 %0, %1, %2" : "=v"(r) : "v"(a), "v"(b));
  return r;
}

#define GLL16(src, dst)                                                     \
  __builtin_amdgcn_global_load_lds(                                         \
      (__attribute__((address_space(1))) void*)(src),                       \
      (__attribute__((address_space(3))) void*)(dst), 16, 0, 0)

// ---------- fused prep: x->bf16, 4 weight transposes, cos/sin table ----------
__global__ void k_prep(const float* __restrict__ x, u16* __restrict__ xb,
                       const float* __restrict__ wq, const float* __restrict__ wk,
                       const float* __restrict__ wv, const float* __restrict__ wo,
                       u16* __restrict__ wqkvT, u16* __restrict__ woT,
                       f32x2* __restrict__ tab) {
  __shared__ float t[32][33];
  const int bid = blockIdx.x, tid = threadIdx.x;
  if (bid < 4096) {
    int i = bid * 256 + tid;
    f32x4 v = *(const f32x4*)(x + (size_t)i * 4);
    u16x4 o;
    o[0] = f2bf(v[0]); o[1] = f2bf(v[1]); o[2] = f2bf(v[2]); o[3] = f2bf(v[3]);
    *(u16x4*)(xb + (size_t)i * 4) = o;
  } else if (bid < 6656) {
    const float* in; u16* out; int N, lb;
    if (bid < 5120)      { in = wq; out = wqkvT;               N = 1024; lb = bid - 4096; }
    else if (bid < 5376) { in = wk; out = wqkvT + 1024 * 1024; N = 256;  lb = bid - 5120; }
    else if (bid < 5632) { in = wv; out = wqkvT + 1280 * 1024; N = 256;  lb = bid - 5376; }
    else                 { in = wo; out = woT;                 N = 1024; lb = bid - 5632; }
    const int kb = (lb & 31) * 32, nb = (lb >> 5) * 32;
    const int tx = tid & 31, ty = tid >> 5;
#pragma unroll
    for (int i = 0; i < 32; i += 8) t[ty + i][tx] = in[(size_t)(kb + ty + i) * N + nb + tx];
    __syncthreads();
#pragma unroll
    for (int i = 0; i < 32; i += 8) out[(size_t)(nb + ty + i) * 1024 + kb + tx] = f2bf(t[tx][ty + i]);
  } else {
    int idx = (bid - 6656) * 256 + tid;  // t*32 + i
    int i = idx & 31, tt = idx >> 5;
    float ang = (float)tt * exp2f(-(float)(2 * i) * (13.28771237954945f / 64.0f));
    float sn, cs; sincosf(ang, &sn, &cs);
    f32x2 v; v.x = cs; v.y = sn;
    tab[idx] = v;
  }
}

// ---------- GEMM1: 64x128 tile, 3-buf counted-vmcnt, fused RoPE epilogue ----------
__global__ __launch_bounds__(256, 3) void k_gemm_qkv(
    const u16* __restrict__ A, const u16* __restrict__ Bt,
    const f32x2* __restrict__ tab,
    u16* __restrict__ qb_, u16* __restrict__ kb_, u16* __restrict__ vT_) {
  constexpr int BK = 32, K = 1024, NT = K / BK;
  __shared__ u16 As[3][64 * BK];
  __shared__ u16 Bs[3][128 * BK];
  const int tid = threadIdx.x;
  const int lane = tid & 63, wid = tid >> 6;
  const int wr = wid >> 1, wc = wid & 1;
  const int l15 = lane & 15, lhi = lane >> 4;
  const int bm = blockIdx.x * 64, bn = blockIdx.y * 128;
  const int srow = tid >> 2, scol = (tid & 3) * 8;
  const u16* ga = A + (size_t)(bm + srow) * K + scol;
  const u16* gb = Bt + (size_t)(bn + srow) * K + scol;
  f32x4 acc[2][4] = {};
  const int aoff = (wr * 32 + l15) * BK + lhi * 8;
  const int boff = (wc * 64 + l15) * BK + lhi * 8;
#pragma unroll
  for (int p = 0; p < 2; p++) {
    GLL16(ga + p * BK, &As[p][tid * 8]);
    GLL16(gb + p * BK, &Bs[p][tid * 8]);
    GLL16(gb + (size_t)64 * K + p * BK, &Bs[p][2048 + tid * 8]);
  }
  int cur = 0, nxt = 2;
  for (int k = 0; k < NT; ++k) {
    if (k + 1 < NT) asm volatile("s_waitcnt vmcnt(3)" ::: "memory");
    else            asm volatile("s_waitcnt vmcnt(0)" ::: "memory");
    __builtin_amdgcn_s_barrier();
    if (k + 2 < NT) {
      const int k2 = (k + 2) * BK;
      GLL16(ga + k2, &As[nxt][tid * 8]);
      GLL16(gb + k2, &Bs[nxt][tid * 8]);
      GLL16(gb + (size_t)64 * K + k2, &Bs[nxt][2048 + tid * 8]);
    }
    bf16x8 af[2], bfr[4];
#pragma unroll
    for (int i = 0; i < 2; i++) af[i] = *(const bf16x8*)&As[cur][aoff + i * 16 * BK];
#pragma unroll
    for (int j = 0; j < 4; j++) bfr[j] = *(const bf16x8*)&Bs[cur][boff + j * 16 * BK];
#pragma unroll
    for (int i = 0; i < 2; i++)
#pragma unroll
      for (int j = 0; j < 4; j++)
        acc[i][j] = __builtin_amdgcn_mfma_f32_16x16x32_bf16(af[i], bfr[j], acc[i][j], 0, 0, 0);
    cur = (cur == 2) ? 0 : cur + 1;
    nxt = (nxt == 2) ? 0 : nxt + 1;
  }
  // ---- fused epilogue ----
  const int crow0 = bm + wr * 32 + lhi * 4;
  const int bsel = (blockIdx.x >= 32) ? 1 : 0;
  const int hg = (bn >> 6) + wc;
  if (blockIdx.y >= 10) {
    u16* dst = vT_ + ((size_t)(bsel * KV_C + (hg - 20)) * 64) * T_C;
#pragma unroll
    for (int j = 0; j < 4; j++) {
      const int d = l15 + j * 16;
#pragma unroll
      for (int i = 0; i < 2; i++) {
        const int t2 = (crow0 + i * 16) & 2047;
        u16x4 pk;
#pragma unroll
        for (int r = 0; r < 4; r++) pk[r] = f2bf(acc[i][j][r]);
        *(u16x4*)&dst[(size_t)d * T_C + t2] = pk;
      }
    }
  } else {
    const bool isq = (blockIdx.y < 8);
    u16* dst = isq ? (qb_ + ((size_t)(bsel * H_C + hg) * T_C) * 64)
                   : (kb_ + ((size_t)(bsel * KV_C + (hg - 16)) * T_C) * 64);
    const float sc = isq ? (0.125f * 1.4426950408889634f) : 1.0f;
    const int par = l15 & 1;
#pragma unroll
    for (int j = 0; j < 4; j++) {
      const int d = l15 + j * 16;
      const int ir = (l15 >> 1) + j * 8;
#pragma unroll
      for (int i = 0; i < 2; i++)
#pragma unroll
        for (int r = 0; r < 4; r++) {
          const int t2 = (crow0 + i * 16 + r) & 2047;
          float v = acc[i][j][r];
          float p = __shfl_xor(v, 1, 64);
          f32x2 cs = tab[t2 * 32 + ir];
          float sgn = par ? cs.y : -cs.y;
          dst[(size_t)t2 * 64 + d] = f2bf((v * cs.x + p * sgn) * sc);
        }
    }
  }
}

// ---------- GEMM2: 64x128 tile, 3-buf counted-vmcnt ----------
__global__ __launch_bounds__(256, 3) void k_gemm_bt(
    const u16* __restrict__ A, const u16* __restrict__ Bt, float* __restrict__ C,
    int M, int N, int K) {
  constexpr int BK = 32;
  __shared__ u16 As[3][64 * BK];
  __shared__ u16 Bs[3][128 * BK];
  const int tid = threadIdx.x;
  const int lane = tid & 63, wid = tid >> 6;
  const int wr = wid >> 1, wc = wid & 1;
  const int l15 = lane & 15, lhi = lane >> 4;
  const int bm = blockIdx.x * 64, bn = blockIdx.y * 128;
  const int srow = tid >> 2, scol = (tid & 3) * 8;
  const u16* ga = A + (size_t)(bm + srow) * K + scol;
  const u16* gb = Bt + (size_t)(bn + srow) * K + scol;
  f32x4 acc[2][4] = {};
  const int aoff = (wr * 32 + l15) * BK + lhi * 8;
  const int boff = (wc * 64 + l15) * BK + lhi * 8;
  const int NT = K / BK;
#pragma unroll
  for (int p = 0; p < 2; p++) {
    GLL16(ga + p * BK, &As[p][tid * 8]);
    GLL16(gb + p * BK, &Bs[p][tid * 8]);
    GLL16(gb + (size_t)64 * K + p * BK, &Bs[p][2048 + tid * 8]);
  }
  int cur = 0, nxt = 2;
  for (int k = 0; k < NT; ++k) {
    if (k + 1 < NT) asm volatile("s_waitcnt vmcnt(3)" ::: "memory");
    else            asm volatile("s_waitcnt vmcnt(0)" ::: "memory");
    __builtin_amdgcn_s_barrier();
    if (k + 2 < NT) {
      const int k2 = (k + 2) * BK;
      GLL16(ga + k2, &As[nxt][tid * 8]);
      GLL16(gb + k2, &Bs[nxt][tid * 8]);
      GLL16(gb + (size_t)64 * K + k2, &Bs[nxt][2048 + tid * 8]);
    }
    bf16x8 af[2], bfr[4];
#pragma unroll
    for (int i = 0; i < 2; i++) af[i] = *(const bf16x8*)&As[cur][aoff + i * 16 * BK];
#pragma unroll
    for (int j = 0; j < 4; j++) bfr[j] = *(const bf16x8*)&Bs[cur][boff + j * 16 * BK];
#pragma unroll
    for (int i = 0; i < 2; i++)
#pragma unroll
      for (int j = 0; j < 4; j++)
        acc[i][j] = __builtin_amdgcn_mfma_f32_16x16x32_bf16(af[i], bfr[j], acc[i][j], 0, 0, 0);
    cur = (cur == 2) ? 0 : cur + 1;
    nxt = (nxt == 2) ? 0 : nxt + 1;
  }
  const int crow0 = bm + wr * 32 + lhi * 4, ccol0 = bn + wc * 64 + l15;
#pragma unroll
  for (int i = 0; i < 2; i++)
#pragma unroll
    for (int j = 0; j < 4; j++)
#pragma unroll
      for (int r = 0; r < 4; r++)
        C[(size_t)(crow0 + i * 16 + r) * N + ccol0 + j * 16] = acc[i][j][r];
}

// ---------- causal flash attention v9 = v5 + defer-max THR=8 (T13) ----------
// v5 (R13-proven, 47.2 us) with ONE change: the rescale block (1 exp2 +
// 4 ds_bpermute + 17 mults) fires only when tmax > m + 8 (exact: P <= 2^8,
// the l-division cancels the scale).
__global__ __launch_bounds__(256, 4) void k_attn(
    const u16* __restrict__ q_bf, const u16* __restrict__ k_bf,
    const u16* __restrict__ vT_bf, u16* __restrict__ att_bf) {
  __shared__ __align__(16) char lds[40960];
  const int bid = blockIdx.x;
  const int g = bid >> 5, g0 = g & 7, gs = g >> 3;
  const int qb = (gs == 0) ? (31 - g0) : (gs == 1) ? g0 : (gs == 2) ? (23 - g0) : (8 + g0);
  const int hb = bid & 31;
  const int h = hb & 15, b = hb >> 4;
  const int kvh = h >> 2;
  const int tid = threadIdx.x, lane = tid & 63, w = tid >> 6;
  const int l15 = lane & 15, lhi = lane >> 4;
  const u16* Qg = q_bf + ((size_t)((b * H_C + h) * T_C) + qb * 64) * 64;
  const u16* Kg = k_bf + ((size_t)((b * KV_C + kvh) * T_C)) * 64;
  const u16* Vg = vT_bf + (size_t)(b * KV_C + kvh) * 64 * T_C;  // [64][T]

  bf16x8 qf[2];
  const int qrow = w * 16 + l15;
#pragma unroll
  for (int kc = 0; kc < 2; kc++)
    qf[kc] = *(const bf16x8*)&Qg[(size_t)qrow * 64 + kc * 32 + lhi * 8];

  f32x4 o[4] = {};
  float m = -1e30f, lsum = 0.f;

  const int nt = qb + 1;
  const int r0 = tid >> 3, j0 = tid & 7;
  const int r1 = r0 + 32;
  const int wb0 = r0 * 128 + ((j0 * 16) ^ ((r0 & 7) << 4));
  const int wb1 = r1 * 128 + ((j0 * 16) ^ ((r1 & 7) << 4));
  char* psb = lds + 0x8000 + w * 0x800;
  const int psw = (l15 & 7) << 4;

  bf16x8 kr0, kr1, vr0, vr1;
  kr0 = *(const bf16x8*)&Kg[(size_t)r0 * 64 + j0 * 8];
  kr1 = *(const bf16x8*)&Kg[(size_t)r1 * 64 + j0 * 8];
  vr0 = *(const bf16x8*)&Vg[(size_t)r0 * T_C + j0 * 8];
  vr1 = *(const bf16x8*)&Vg[(size_t)r1 * T_C + j0 * 8];
  *(bf16x8*)(lds + wb0) = kr0;
  *(bf16x8*)(lds + wb1) = kr1;
  *(bf16x8*)(lds + 0x4000 + wb0) = vr0;
  *(bf16x8*)(lds + 0x4000 + wb1) = vr1;
  __syncthreads();

  for (int it = 0; it < nt; ++it) {
    const int t0 = it * 64;
    const int coff = (it & 1) * 0x2000;
    if (it + 1 < nt) {
      const int t1 = t0 + 64;
      kr0 = *(const bf16x8*)&Kg[(size_t)(t1 + r0) * 64 + j0 * 8];
      kr1 = *(const bf16x8*)&Kg[(size_t)(t1 + r1) * 64 + j0 * 8];
      vr0 = *(const bf16x8*)&Vg[(size_t)r0 * T_C + t1 + j0 * 8];
      vr1 = *(const bf16x8*)&Vg[(size_t)r1 * T_C + t1 + j0 * 8];
    }
    // ---- S^T = K Q^T (swapped operands; q = l15, key = nf*16+lhi*4+r) ----
    bf16x8 kf[4][2];
#pragma unroll
    for (int nf = 0; nf < 4; nf++)
#pragma unroll
      for (int kc = 0; kc < 2; kc++) {
        const int row = nf * 16 + l15;
        kf[nf][kc] = *(const bf16x8*)(lds + coff + row * 128 +
                                      ((kc * 64 + lhi * 16) ^ ((l15 & 7) << 4)));
      }
    f32x4 s[4] = {};
    __builtin_amdgcn_s_setprio(1);
#pragma unroll
    for (int nf = 0; nf < 4; nf++)
#pragma unroll
      for (int kc = 0; kc < 2; kc++)
        s[nf] = __builtin_amdgcn_mfma_f32_16x16x32_bf16(kf[nf][kc], qf[kc], s[nf], 0, 0, 0);
    __builtin_amdgcn_s_setprio(0);
    // ---- causal mask on diagonal tile: key > q ----
    if (it == nt - 1) {
      const int qg = w * 16 + l15;
#pragma unroll
      for (int nf = 0; nf < 4; nf++) {
        const int kb2 = nf * 16 + lhi * 4;
#pragma unroll
        for (int r = 0; r < 4; r++)
          if (kb2 + r > qg) s[nf][r] = -1e30f;
      }
    }
    // ---- online softmax: lane owns q-row; 2-shfl reduce over lhi ----
    float a0 = fmaxf(fmaxf(s[0][0], s[0][1]), fmaxf(s[0][2], s[0][3]));
    float a1 = fmaxf(fmaxf(s[1][0], s[1][1]), fmaxf(s[1][2], s[1][3]));
    float a2 = fmaxf(fmaxf(s[2][0], s[2][1]), fmaxf(s[2][2], s[2][3]));
    float a3 = fmaxf(fmaxf(s[3][0], s[3][1]), fmaxf(s[3][2], s[3][3]));
    float tmax = fmaxf(fmaxf(a0, a1), fmaxf(a2, a3));
    tmax = fmaxf(tmax, __shfl_xor(tmax, 16, 64));
    tmax = fmaxf(tmax, __shfl_xor(tmax, 32, 64));
    if (__any(tmax > m + 8.0f)) {  // defer-max: rescale only on real jumps
      float mn = fmaxf(m, tmax);
      float alpha = __builtin_exp2f(m - mn);
      m = mn;
      lsum *= alpha;
      float ar[4];
#pragma unroll
      for (int r = 0; r < 4; r++) ar[r] = __shfl(alpha, lhi * 4 + r, 64);
#pragma unroll
      for (int nf = 0; nf < 4; nf++)
#pragma unroll
        for (int r = 0; r < 4; r++) o[nf][r] *= ar[r];
    }
    // ---- P = exp2(S - m), pack bf16 pairs, 8x ds_write_b32 ----
#pragma unroll
    for (int nf = 0; nf < 4; nf++) {
      float p0 = __builtin_exp2f(s[nf][0] - m);
      float p1 = __builtin_exp2f(s[nf][1] - m);
      float p2 = __builtin_exp2f(s[nf][2] - m);
      float p3 = __builtin_exp2f(s[nf][3] - m);
      lsum += (p0 + p1) + (p2 + p3);
      unsigned lo = cvtpk(p0, p1), hi = cvtpk(p2, p3);
      const int pb = ((nf * 32 + lhi * 8) ^ psw) + l15 * 128;
      *(unsigned*)(psb + pb) = lo;
      *(unsigned*)(psb + pb + 4) = hi;
    }
    asm volatile("s_waitcnt lgkmcnt(0)" ::: "memory");
    __builtin_amdgcn_sched_barrier(0);
    // ---- O += P V ----
    __builtin_amdgcn_s_setprio(1);
#pragma unroll
    for (int kc = 0; kc < 2; kc++) {
      bf16x8 pa = *(const bf16x8*)(psb + l15 * 128 +
                                   ((kc * 64 + lhi * 16) ^ ((l15 & 7) << 4)));
#pragma unroll
      for (int nf = 0; nf < 4; nf++) {
        bf16x8 vf = *(const bf16x8*)(lds + 0x4000 + coff + (nf * 16 + l15) * 128 +
                                     ((kc * 64 + lhi * 16) ^ ((l15 & 7) << 4)));
        o[nf] = __builtin_amdgcn_mfma_f32_16x16x32_bf16(pa, vf, o[nf], 0, 0, 0);
      }
    }
    __builtin_amdgcn_s_setprio(0);
    if (it + 1 < nt) {
      const int noff = ((it + 1) & 1) * 0x2000;
      *(bf16x8*)(lds + noff + wb0) = kr0;
      *(bf16x8*)(lds + noff + wb1) = kr1;
      *(bf16x8*)(lds + 0x4000 + noff + wb0) = vr0;
      *(bf16x8*)(lds + 0x4000 + noff + wb1) = vr1;
    }
    __syncthreads();
  }
  // ---- epilogue: reduce lsum over lhi, redistribute inv to O rows ----
  lsum += __shfl_xor(lsum, 16, 64);
  lsum += __shfl_xor(lsum, 32, 64);
  float inv = 1.0f / lsum;
  float invr[4];
#pragma unroll
  for (int r = 0; r < 4; r++) invr[r] = __shfl(inv, lhi * 4 + r, 64);
  const int trow = qb * 64 + w * 16 + lhi * 4;
  const size_t obase = ((size_t)(b * T_C) + trow) * 1024 + h * 64;
#pragma unroll
  for (int nf = 0; nf < 4; nf++)
#pragma unroll
    for (int r = 0; r < 4; r++)
      att_bf[obase + (size_t)r * 1024 + nf * 16 + l15] = f2bf(o[nf][r] * invr[r]);
}

extern "C" void kernel_launch(void* const* d_in, const int* in_sizes, int n_in,
                              void* d_out, int out_size, void* d_ws, size_t ws_size,
                              hipStream_t stream) {
  const float* x  = (const float*)d_in[0];
  const float* wq = (const float*)d_in[2];
  const float* wk = (const float*)d_in[3];
  const float* wv = (const float*)d_in[4];
  const float* wo = (const float*)d_in[5];
  float* out = (float*)d_out;

  char* ws = (char*)d_ws;
  u16*   xb    = (u16*)(ws);                          //  8 MiB
  u16*   wqkvT = (u16*)(ws + (8ull  << 20));          //  3 MiB
  u16*   woT   = (u16*)(ws + (11ull << 20));          //  2 MiB
  u16*   vT_bf = (u16*)(ws + (13ull << 20));          //  2 MiB
  f32x2* tab   = (f32x2*)(ws + (15ull << 20));        // 512 KiB
  u16*   q_bf  = (u16*)(ws + (37ull << 20));          //  8 MiB
  u16*   k_bf  = (u16*)(ws + (45ull << 20));          //  2 MiB
  u16*   attb  = (u16*)(ws + (49ull << 20));          //  8 MiB

  k_prep<<<6912, 256, 0, stream>>>(x, xb, wq, wk, wv, wo, wqkvT, woT, tab);
  k_gemm_qkv<<<dim3(64, 12), 256, 0, stream>>>(xb, wqkvT, tab, q_bf, k_bf, vT_bf);
  k_attn<<<1024, 256, 0, stream>>>(q_bf, k_bf, vT_bf, attb);
  k_gemm_bt<<<dim3(64, 8), 256, 0, stream>>>(attb, woT, out, 4096, 1024, 1024);
}

// Round 17
// 96.737 us; speedup vs baseline: 1.0930x; 1.0100x over previous
//
#include <hip/hip_runtime.h>
#include <cstdint>

typedef unsigned short u16;
typedef __attribute__((ext_vector_type(2))) float f32x2;
typedef __attribute__((ext_vector_type(4))) float f32x4;
typedef __attribute__((ext_vector_type(8))) short bf16x8;
typedef __attribute__((ext_vector_type(4))) u16 u16x4;

#define B_C 2
#define T_C 2048
#define H_C 16
#define KV_C 4

__device__ __forceinline__ u16 f2bf(float f) {
  unsigned u = __builtin_bit_cast(unsigned, f);
  u = (u + 0x7fffu + ((u >> 16) & 1u)) >> 16;
  return (u16)u;
}

__device__ __forceinline__ unsigned cvtpk(float a, float b) {
  unsigned r;
  asm("v_cvt_pk_bf16_f32 %0, %1, %2" : "=v"(r) : "v"(a), "v"(b));
  return r;
}

#define GLL16(src, dst)                                                     \
  __builtin_amdgcn_global_load_lds(                                         \
      (__attribute__((address_space(1))) void*)(src),                       \
      (__attribute__((address_space(3))) void*)(dst), 16, 0, 0)

// ---------- fused prep: x->bf16, 4 weight transposes, cos/sin table ----------
__global__ void k_prep(const float* __restrict__ x, u16* __restrict__ xb,
                       const float* __restrict__ wq, const float* __restrict__ wk,
                       const float* __restrict__ wv, const float* __restrict__ wo,
                       u16* __restrict__ wqkvT, u16* __restrict__ woT,
                       f32x2* __restrict__ tab) {
  __shared__ float t[32][33];
  const int bid = blockIdx.x, tid = threadIdx.x;
  if (bid < 4096) {
    int i = bid * 256 + tid;
    f32x4 v = *(const f32x4*)(x + (size_t)i * 4);
    u16x4 o;
    o[0] = f2bf(v[0]); o[1] = f2bf(v[1]); o[2] = f2bf(v[2]); o[3] = f2bf(v[3]);
    *(u16x4*)(xb + (size_t)i * 4) = o;
  } else if (bid < 6656) {
    const float* in; u16* out; int N, lb;
    if (bid < 5120)      { in = wq; out = wqkvT;               N = 1024; lb = bid - 4096; }
    else if (bid < 5376) { in = wk; out = wqkvT + 1024 * 1024; N = 256;  lb = bid - 5120; }
    else if (bid < 5632) { in = wv; out = wqkvT + 1280 * 1024; N = 256;  lb = bid - 5376; }
    else                 { in = wo; out = woT;                 N = 1024; lb = bid - 5632; }
    const int kb = (lb & 31) * 32, nb = (lb >> 5) * 32;
    const int tx = tid & 31, ty = tid >> 5;
#pragma unroll
    for (int i = 0; i < 32; i += 8) t[ty + i][tx] = in[(size_t)(kb + ty + i) * N + nb + tx];
    __syncthreads();
#pragma unroll
    for (int i = 0; i < 32; i += 8) out[(size_t)(nb + ty + i) * 1024 + kb + tx] = f2bf(t[tx][ty + i]);
  } else {
    int idx = (bid - 6656) * 256 + tid;  // t*32 + i
    int i = idx & 31, tt = idx >> 5;
    float ang = (float)tt * exp2f(-(float)(2 * i) * (13.28771237954945f / 64.0f));
    float sn, cs; sincosf(ang, &sn, &cs);
    f32x2 v; v.x = cs; v.y = sn;
    tab[idx] = v;
  }
}

// ---------- GEMM1: 64x128 tile, 3-buf counted-vmcnt, T2 LDS swizzle,
//            fused RoPE epilogue ----------
// Swizzle (m173 pattern): LDS dest linear; global source 16B-chunk column
// is chunk^((row>>1)&3); fragment reads use (lhi ^ ((l15>>1)&3)).
__global__ __launch_bounds__(256, 3) void k_gemm_qkv(
    const u16* __restrict__ A, const u16* __restrict__ Bt,
    const f32x2* __restrict__ tab,
    u16* __restrict__ qb_, u16* __restrict__ kb_, u16* __restrict__ vT_) {
  constexpr int BK = 32, K = 1024, NT = K / BK;
  __shared__ u16 As[3][64 * BK];
  __shared__ u16 Bs[3][128 * BK];
  const int tid = threadIdx.x;
  const int lane = tid & 63, wid = tid >> 6;
  const int wr = wid >> 1, wc = wid & 1;
  const int l15 = lane & 15, lhi = lane >> 4;
  const int bm = blockIdx.x * 64, bn = blockIdx.y * 128;
  const int srow = tid >> 2;
  const int scol = (((tid & 3) ^ ((tid >> 3) & 3))) * 8;  // pre-swizzled source
  const u16* ga = A + (size_t)(bm + srow) * K + scol;
  const u16* gb = Bt + (size_t)(bn + srow) * K + scol;
  f32x4 acc[2][4] = {};
  const int csw = (lhi ^ ((l15 >> 1) & 3)) * 8;           // swizzled read chunk
  const int aoff = (wr * 32 + l15) * BK + csw;
  const int boff = (wc * 64 + l15) * BK + csw;
#pragma unroll
  for (int p = 0; p < 2; p++) {
    GLL16(ga + p * BK, &As[p][tid * 8]);
    GLL16(gb + p * BK, &Bs[p][tid * 8]);
    GLL16(gb + (size_t)64 * K + p * BK, &Bs[p][2048 + tid * 8]);
  }
  int cur = 0, nxt = 2;
  for (int k = 0; k < NT; ++k) {
    if (k + 1 < NT) asm volatile("s_waitcnt vmcnt(3)" ::: "memory");
    else            asm volatile("s_waitcnt vmcnt(0)" ::: "memory");
    __builtin_amdgcn_s_barrier();
    if (k + 2 < NT) {
      const int k2 = (k + 2) * BK;
      GLL16(ga + k2, &As[nxt][tid * 8]);
      GLL16(gb + k2, &Bs[nxt][tid * 8]);
      GLL16(gb + (size_t)64 * K + k2, &Bs[nxt][2048 + tid * 8]);
    }
    bf16x8 af[2], bfr[4];
#pragma unroll
    for (int i = 0; i < 2; i++) af[i] = *(const bf16x8*)&As[cur][aoff + i * 16 * BK];
#pragma unroll
    for (int j = 0; j < 4; j++) bfr[j] = *(const bf16x8*)&Bs[cur][boff + j * 16 * BK];
#pragma unroll
    for (int i = 0; i < 2; i++)
#pragma unroll
      for (int j = 0; j < 4; j++)
        acc[i][j] = __builtin_amdgcn_mfma_f32_16x16x32_bf16(af[i], bfr[j], acc[i][j], 0, 0, 0);
    cur = (cur == 2) ? 0 : cur + 1;
    nxt = (nxt == 2) ? 0 : nxt + 1;
  }
  // ---- fused epilogue ----
  const int crow0 = bm + wr * 32 + lhi * 4;
  const int bsel = (blockIdx.x >= 32) ? 1 : 0;
  const int hg = (bn >> 6) + wc;
  if (blockIdx.y >= 10) {
    u16* dst = vT_ + ((size_t)(bsel * KV_C + (hg - 20)) * 64) * T_C;
#pragma unroll
    for (int j = 0; j < 4; j++) {
      const int d = l15 + j * 16;
#pragma unroll
      for (int i = 0; i < 2; i++) {
        const int t2 = (crow0 + i * 16) & 2047;
        u16x4 pk;
#pragma unroll
        for (int r = 0; r < 4; r++) pk[r] = f2bf(acc[i][j][r]);
        *(u16x4*)&dst[(size_t)d * T_C + t2] = pk;
      }
    }
  } else {
    const bool isq = (blockIdx.y < 8);
    u16* dst = isq ? (qb_ + ((size_t)(bsel * H_C + hg) * T_C) * 64)
                   : (kb_ + ((size_t)(bsel * KV_C + (hg - 16)) * T_C) * 64);
    const float sc = isq ? (0.125f * 1.4426950408889634f) : 1.0f;
    const int par = l15 & 1;
#pragma unroll
    for (int j = 0; j < 4; j++) {
      const int d = l15 + j * 16;
      const int ir = (l15 >> 1) + j * 8;
#pragma unroll
      for (int i = 0; i < 2; i++)
#pragma unroll
        for (int r = 0; r < 4; r++) {
          const int t2 = (crow0 + i * 16 + r) & 2047;
          float v = acc[i][j][r];
          float p = __shfl_xor(v, 1, 64);
          f32x2 cs = tab[t2 * 32 + ir];
          float sgn = par ? cs.y : -cs.y;
          dst[(size_t)t2 * 64 + d] = f2bf((v * cs.x + p * sgn) * sc);
        }
    }
  }
}

// ---------- GEMM2: 64x128 tile, 3-buf counted-vmcnt, T2 LDS swizzle ----------
__global__ __launch_bounds__(256, 3) void k_gemm_bt(
    const u16* __restrict__ A, const u16* __restrict__ Bt, float* __restrict__ C,
    int M, int N, int K) {
  constexpr int BK = 32;
  __shared__ u16 As[3][64 * BK];
  __shared__ u16 Bs[3][128 * BK];
  const int tid = threadIdx.x;
  const int lane = tid & 63, wid = tid >> 6;
  const int wr = wid >> 1, wc = wid & 1;
  const int l15 = lane & 15, lhi = lane >> 4;
  const int bm = blockIdx.x * 64, bn = blockIdx.y * 128;
  const int srow = tid >> 2;
  const int scol = (((tid & 3) ^ ((tid >> 3) & 3))) * 8;
  const u16* ga = A + (size_t)(bm + srow) * K + scol;
  const u16* gb = Bt + (size_t)(bn + srow) * K + scol;
  f32x4 acc[2][4] = {};
  const int csw = (lhi ^ ((l15 >> 1) & 3)) * 8;
  const int aoff = (wr * 32 + l15) * BK + csw;
  const int boff = (wc * 64 + l15) * BK + csw;
  const int NT = K / BK;
#pragma unroll
  for (int p = 0; p < 2; p++) {
    GLL16(ga + p * BK, &As[p][tid * 8]);
    GLL16(gb + p * BK, &Bs[p][tid * 8]);
    GLL16(gb + (size_t)64 * K + p * BK, &Bs[p][2048 + tid * 8]);
  }
  int cur = 0, nxt = 2;
  for (int k = 0; k < NT; ++k) {
    if (k + 1 < NT) asm volatile("s_waitcnt vmcnt(3)" ::: "memory");
    else            asm volatile("s_waitcnt vmcnt(0)" ::: "memory");
    __builtin_amdgcn_s_barrier();
    if (k + 2 < NT) {
      const int k2 = (k + 2) * BK;
      GLL16(ga + k2, &As[nxt][tid * 8]);
      GLL16(gb + k2, &Bs[nxt][tid * 8]);
      GLL16(gb + (size_t)64 * K + k2, &Bs[nxt][2048 + tid * 8]);
    }
    bf16x8 af[2], bfr[4];
#pragma unroll
    for (int i = 0; i < 2; i++) af[i] = *(const bf16x8*)&As[cur][aoff + i * 16 * BK];
#pragma unroll
    for (int j = 0; j < 4; j++) bfr[j] = *(const bf16x8*)&Bs[cur][boff + j * 16 * BK];
#pragma unroll
    for (int i = 0; i < 2; i++)
#pragma unroll
      for (int j = 0; j < 4; j++)
        acc[i][j] = __builtin_amdgcn_mfma_f32_16x16x32_bf16(af[i], bfr[j], acc[i][j], 0, 0, 0);
    cur = (cur == 2) ? 0 : cur + 1;
    nxt = (nxt == 2) ? 0 : nxt + 1;
  }
  const int crow0 = bm + wr * 32 + lhi * 4, ccol0 = bn + wc * 64 + l15;
#pragma unroll
  for (int i = 0; i < 2; i++)
#pragma unroll
    for (int j = 0; j < 4; j++)
#pragma unroll
      for (int r = 0; r < 4; r++)
        C[(size_t)(crow0 + i * 16 + r) * N + ccol0 + j * 16] = acc[i][j][r];
}

// ---------- causal flash attention v9 = v5 + defer-max THR=8 (R16-proven) ----------
__global__ __launch_bounds__(256, 4) void k_attn(
    const u16* __restrict__ q_bf, const u16* __restrict__ k_bf,
    const u16* __restrict__ vT_bf, u16* __restrict__ att_bf) {
  __shared__ __align__(16) char lds[40960];
  const int bid = blockIdx.x;
  const int g = bid >> 5, g0 = g & 7, gs = g >> 3;
  const int qb = (gs == 0) ? (31 - g0) : (gs == 1) ? g0 : (gs == 2) ? (23 - g0) : (8 + g0);
  const int hb = bid & 31;
  const int h = hb & 15, b = hb >> 4;
  const int kvh = h >> 2;
  const int tid = threadIdx.x, lane = tid & 63, w = tid >> 6;
  const int l15 = lane & 15, lhi = lane >> 4;
  const u16* Qg = q_bf + ((size_t)((b * H_C + h) * T_C) + qb * 64) * 64;
  const u16* Kg = k_bf + ((size_t)((b * KV_C + kvh) * T_C)) * 64;
  const u16* Vg = vT_bf + (size_t)(b * KV_C + kvh) * 64 * T_C;  // [64][T]

  bf16x8 qf[2];
  const int qrow = w * 16 + l15;
#pragma unroll
  for (int kc = 0; kc < 2; kc++)
    qf[kc] = *(const bf16x8*)&Qg[(size_t)qrow * 64 + kc * 32 + lhi * 8];

  f32x4 o[4] = {};
  float m = -1e30f, lsum = 0.f;

  const int nt = qb + 1;
  const int r0 = tid >> 3, j0 = tid & 7;
  const int r1 = r0 + 32;
  const int wb0 = r0 * 128 + ((j0 * 16) ^ ((r0 & 7) << 4));
  const int wb1 = r1 * 128 + ((j0 * 16) ^ ((r1 & 7) << 4));
  char* psb = lds + 0x8000 + w * 0x800;
  const int psw = (l15 & 7) << 4;

  bf16x8 kr0, kr1, vr0, vr1;
  kr0 = *(const bf16x8*)&Kg[(size_t)r0 * 64 + j0 * 8];
  kr1 = *(const bf16x8*)&Kg[(size_t)r1 * 64 + j0 * 8];
  vr0 = *(const bf16x8*)&Vg[(size_t)r0 * T_C + j0 * 8];
  vr1 = *(const bf16x8*)&Vg[(size_t)r1 * T_C + j0 * 8];
  *(bf16x8*)(lds + wb0) = kr0;
  *(bf16x8*)(lds + wb1) = kr1;
  *(bf16x8*)(lds + 0x4000 + wb0) = vr0;
  *(bf16x8*)(lds + 0x4000 + wb1) = vr1;
  __syncthreads();

  for (int it = 0; it < nt; ++it) {
    const int t0 = it * 64;
    const int coff = (it & 1) * 0x2000;
    if (it + 1 < nt) {
      const int t1 = t0 + 64;
      kr0 = *(const bf16x8*)&Kg[(size_t)(t1 + r0) * 64 + j0 * 8];
      kr1 = *(const bf16x8*)&Kg[(size_t)(t1 + r1) * 64 + j0 * 8];
      vr0 = *(const bf16x8*)&Vg[(size_t)r0 * T_C + t1 + j0 * 8];
      vr1 = *(const bf16x8*)&Vg[(size_t)r1 * T_C + t1 + j0 * 8];
    }
    // ---- S^T = K Q^T (swapped operands; q = l15, key = nf*16+lhi*4+r) ----
    bf16x8 kf[4][2];
#pragma unroll
    for (int nf = 0; nf < 4; nf++)
#pragma unroll
      for (int kc = 0; kc < 2; kc++) {
        const int row = nf * 16 + l15;
        kf[nf][kc] = *(const bf16x8*)(lds + coff + row * 128 +
                                      ((kc * 64 + lhi * 16) ^ ((l15 & 7) << 4)));
      }
    f32x4 s[4] = {};
    __builtin_amdgcn_s_setprio(1);
#pragma unroll
    for (int nf = 0; nf < 4; nf++)
#pragma unroll
      for (int kc = 0; kc < 2; kc++)
        s[nf] = __builtin_amdgcn_mfma_f32_16x16x32_bf16(kf[nf][kc], qf[kc], s[nf], 0, 0, 0);
    __builtin_amdgcn_s_setprio(0);
    // ---- causal mask on diagonal tile: key > q ----
    if (it == nt - 1) {
      const int qg = w * 16 + l15;
#pragma unroll
      for (int nf = 0; nf < 4; nf++) {
        const int kb2 = nf * 16 + lhi * 4;
#pragma unroll
        for (int r = 0; r < 4; r++)
          if (kb2 + r > qg) s[nf][r] = -1e30f;
      }
    }
    // ---- online softmax: lane owns q-row; 2-shfl reduce over lhi ----
    float a0 = fmaxf(fmaxf(s[0][0], s[0][1]), fmaxf(s[0][2], s[0][3]));
    float a1 = fmaxf(fmaxf(s[1][0], s[1][1]), fmaxf(s[1][2], s[1][3]));
    float a2 = fmaxf(fmaxf(s[2][0], s[2][1]), fmaxf(s[2][2], s[2][3]));
    float a3 = fmaxf(fmaxf(s[3][0], s[3][1]), fmaxf(s[3][2], s[3][3]));
    float tmax = fmaxf(fmaxf(a0, a1), fmaxf(a2, a3));
    tmax = fmaxf(tmax, __shfl_xor(tmax, 16, 64));
    tmax = fmaxf(tmax, __shfl_xor(tmax, 32, 64));
    if (__any(tmax > m + 8.0f)) {  // defer-max: rescale only on real jumps
      float mn = fmaxf(m, tmax);
      float alpha = __builtin_exp2f(m - mn);
      m = mn;
      lsum *= alpha;
      float ar[4];
#pragma unroll
      for (int r = 0; r < 4; r++) ar[r] = __shfl(alpha, lhi * 4 + r, 64);
#pragma unroll
      for (int nf = 0; nf < 4; nf++)
#pragma unroll
        for (int r = 0; r < 4; r++) o[nf][r] *= ar[r];
    }
    // ---- P = exp2(S - m), pack bf16 pairs, 8x ds_write_b32 ----
#pragma unroll
    for (int nf = 0; nf < 4; nf++) {
      float p0 = __builtin_exp2f(s[nf][0] - m);
      float p1 = __builtin_exp2f(s[nf][1] - m);
      float p2 = __builtin_exp2f(s[nf][2] - m);
      float p3 = __builtin_exp2f(s[nf][3] - m);
      lsum += (p0 + p1) + (p2 + p3);
      unsigned lo = cvtpk(p0, p1), hi = cvtpk(p2, p3);
      const int pb = ((nf * 32 + lhi * 8) ^ psw) + l15 * 128;
      *(unsigned*)(psb + pb) = lo;
      *(unsigned*)(psb + pb + 4) = hi;
    }
    asm volatile("s_waitcnt lgkmcnt(0)" ::: "memory");
    __builtin_amdgcn_sched_barrier(0);
    // ---- O += P V ----
    __builtin_amdgcn_s_setprio(1);
#pragma unroll
    for (int kc = 0; kc < 2; kc++) {
      bf16x8 pa = *(const bf16x8*)(psb + l15 * 128 +
                                   ((kc * 64 + lhi * 16) ^ ((l15 & 7) << 4)));
#pragma unroll
      for (int nf = 0; nf < 4; nf++) {
        bf16x8 vf = *(const bf16x8*)(lds + 0x4000 + coff + (nf * 16 + l15) * 128 +
                                     ((kc * 64 + lhi * 16) ^ ((l15 & 7) << 4)));
        o[nf] = __builtin_amdgcn_mfma_f32_16x16x32_bf16(pa, vf, o[nf], 0, 0, 0);
      }
    }
    __builtin_amdgcn_s_setprio(0);
    if (it + 1 < nt) {
      const int noff = ((it + 1) & 1) * 0x2000;
      *(bf16x8*)(lds + noff + wb0) = kr0;
      *(bf16x8*)(lds + noff + wb1) = kr1;
      *(bf16x8*)(lds + 0x4000 + noff + wb0) = vr0;
      *(bf16x8*)(lds + 0x4000 + noff + wb1) = vr1;
    }
    __syncthreads();
  }
  // ---- epilogue: reduce lsum over lhi, redistribute inv to O rows ----
  lsum += __shfl_xor(lsum, 16, 64);
  lsum += __shfl_xor(lsum, 32, 64);
  float inv = 1.0f / lsum;
  float invr[4];
#pragma unroll
  for (int r = 0; r < 4; r++) invr[r] = __shfl(inv, lhi * 4 + r, 64);
  const int trow = qb * 64 + w * 16 + lhi * 4;
  const size_t obase = ((size_t)(b * T_C) + trow) * 1024 + h * 64;
#pragma unroll
  for (int nf = 0; nf < 4; nf++)
#pragma unroll
    for (int r = 0; r < 4; r++)
      att_bf[obase + (size_t)r * 1024 + nf * 16 + l15] = f2bf(o[nf][r] * invr[r]);
}

extern "C" void kernel_launch(void* const* d_in, const int* in_sizes, int n_in,
                              void* d_out, int out_size, void* d_ws, size_t ws_size,
                              hipStream_t stream) {
  const float* x  = (const float*)d_in[0];
  const float* wq = (const float*)d_in[2];
  const float* wk = (const float*)d_in[3];
  const float* wv = (const float*)d_in[4];
  const float* wo = (const float*)d_in[5];
  float* out = (float*)d_out;

  char* ws = (char*)d_ws;
  u16*   xb    = (u16*)(ws);                          //  8 MiB
  u16*   wqkvT = (u16*)(ws + (8ull  << 20));          //  3 MiB
  u16*   woT   = (u16*)(ws + (11ull << 20));          //  2 MiB
  u16*   vT_bf = (u16*)(ws + (13ull << 20));          //  2 MiB
  f32x2* tab   = (f32x2*)(ws + (15ull << 20));        // 512 KiB
  u16*   q_bf  = (u16*)(ws + (37ull << 20));          //  8 MiB
  u16*   k_bf  = (u16*)(ws + (45ull << 20));          //  2 MiB
  u16*   attb  = (u16*)(ws + (49ull << 20));          //  8 MiB

  k_prep<<<6912, 256, 0, stream>>>(x, xb, wq, wk, wv, wo, wqkvT, woT, tab);
  k_gemm_qkv<<<dim3(64, 12), 256, 0, stream>>>(xb, wqkvT, tab, q_bf, k_bf, vT_bf);
  k_attn<<<1024, 256, 0, stream>>>(q_bf, k_bf, vT_bf, attb);
  k_gemm_bt<<<dim3(64, 8), 256, 0, stream>>>(attb, woT, out, 4096, 1024, 1024);
}

// Round 19
// 96.317 us; speedup vs baseline: 1.0978x; 1.0044x over previous
//
#include <hip/hip_runtime.h>
#include <cstdint>

typedef unsigned short u16;
typedef __attribute__((ext_vector_type(2))) float f32x2;
typedef __attribute__((ext_vector_type(4))) float f32x4;
typedef __attribute__((ext_vector_type(8))) short bf16x8;
typedef __attribute__((ext_vector_type(4))) u16 u16x4;

#define B_C 2
#define T_C 2048
#define H_C 16
#define KV_C 4

__device__ __forceinline__ u16 f2bf(float f) {
  unsigned u = __builtin_bit_cast(unsigned, f);
  u = (u + 0x7fffu + ((u >> 16) & 1u)) >> 16;
  return (u16)u;
}

__device__ __forceinline__ unsigned cvtpk(float a, float b) {
  unsigned r;
  asm("v_cvt_pk_bf16_f32 %0, %1, %2" : "=v"(r) : "v"(a), "v"(b));
  return r;
}

#define GLL16(src, dst)                                                     \
  __builtin_amdgcn_global_load_lds(                                         \
      (__attribute__((address_space(1))) void*)(src),                       \
      (__attribute__((address_space(3))) void*)(dst), 16, 0, 0)

// ---------- fused prep: x->bf16, 4 weight transposes, cos/sin table ----------
__global__ void k_prep(const float* __restrict__ x, u16* __restrict__ xb,
                       const float* __restrict__ wq, const float* __restrict__ wk,
                       const float* __restrict__ wv, const float* __restrict__ wo,
                       u16* __restrict__ wqkvT, u16* __restrict__ woT,
                       f32x2* __restrict__ tab) {
  __shared__ float t[32][33];
  const int bid = blockIdx.x, tid = threadIdx.x;
  if (bid < 4096) {
    int i = bid * 256 + tid;
    f32x4 v = *(const f32x4*)(x + (size_t)i * 4);
    u16x4 o;
    o[0] = f2bf(v[0]); o[1] = f2bf(v[1]); o[2] = f2bf(v[2]); o[3] = f2bf(v[3]);
    *(u16x4*)(xb + (size_t)i * 4) = o;
  } else if (bid < 6656) {
    const float* in; u16* out; int N, lb;
    if (bid < 5120)      { in = wq; out = wqkvT;               N = 1024; lb = bid - 4096; }
    else if (bid < 5376) { in = wk; out = wqkvT + 1024 * 1024; N = 256;  lb = bid - 5120; }
    else if (bid < 5632) { in = wv; out = wqkvT + 1280 * 1024; N = 256;  lb = bid - 5376; }
    else                 { in = wo; out = woT;                 N = 1024; lb = bid - 5632; }
    const int kb = (lb & 31) * 32, nb = (lb >> 5) * 32;
    const int tx = tid & 31, ty = tid >> 5;
#pragma unroll
    for (int i = 0; i < 32; i += 8) t[ty + i][tx] = in[(size_t)(kb + ty + i) * N + nb + tx];
    __syncthreads();
#pragma unroll
    for (int i = 0; i < 32; i += 8) out[(size_t)(nb + ty + i) * 1024 + kb + tx] = f2bf(t[tx][ty + i]);
  } else {
    int idx = (bid - 6656) * 256 + tid;  // t*32 + i
    int i = idx & 31, tt = idx >> 5;
    float ang = (float)tt * exp2f(-(float)(2 * i) * (13.28771237954945f / 64.0f));
    float sn, cs; sincosf(ang, &sn, &cs);
    f32x2 v; v.x = cs; v.y = sn;
    tab[idx] = v;
  }
}

// ---------- GEMM1: 64x128 tile, 3-buf counted-vmcnt, T2 LDS swizzle,
//            fused RoPE epilogue (R17-proven) ----------
__global__ __launch_bounds__(256, 3) void k_gemm_qkv(
    const u16* __restrict__ A, const u16* __restrict__ Bt,
    const f32x2* __restrict__ tab,
    u16* __restrict__ qb_, u16* __restrict__ kb_, u16* __restrict__ vT_) {
  constexpr int BK = 32, K = 1024, NT = K / BK;
  __shared__ u16 As[3][64 * BK];
  __shared__ u16 Bs[3][128 * BK];
  const int tid = threadIdx.x;
  const int lane = tid & 63, wid = tid >> 6;
  const int wr = wid >> 1, wc = wid & 1;
  const int l15 = lane & 15, lhi = lane >> 4;
  const int bm = blockIdx.x * 64, bn = blockIdx.y * 128;
  const int srow = tid >> 2;
  const int scol = (((tid & 3) ^ ((tid >> 3) & 3))) * 8;  // pre-swizzled source
  const u16* ga = A + (size_t)(bm + srow) * K + scol;
  const u16* gb = Bt + (size_t)(bn + srow) * K + scol;
  f32x4 acc[2][4] = {};
  const int csw = (lhi ^ ((l15 >> 1) & 3)) * 8;           // swizzled read chunk
  const int aoff = (wr * 32 + l15) * BK + csw;
  const int boff = (wc * 64 + l15) * BK + csw;
#pragma unroll
  for (int p = 0; p < 2; p++) {
    GLL16(ga + p * BK, &As[p][tid * 8]);
    GLL16(gb + p * BK, &Bs[p][tid * 8]);
    GLL16(gb + (size_t)64 * K + p * BK, &Bs[p][2048 + tid * 8]);
  }
  int cur = 0, nxt = 2;
  for (int k = 0; k < NT; ++k) {
    if (k + 1 < NT) asm volatile("s_waitcnt vmcnt(3)" ::: "memory");
    else            asm volatile("s_waitcnt vmcnt(0)" ::: "memory");
    __builtin_amdgcn_s_barrier();
    if (k + 2 < NT) {
      const int k2 = (k + 2) * BK;
      GLL16(ga + k2, &As[nxt][tid * 8]);
      GLL16(gb + k2, &Bs[nxt][tid * 8]);
      GLL16(gb + (size_t)64 * K + k2, &Bs[nxt][2048 + tid * 8]);
    }
    bf16x8 af[2], bfr[4];
#pragma unroll
    for (int i = 0; i < 2; i++) af[i] = *(const bf16x8*)&As[cur][aoff + i * 16 * BK];
#pragma unroll
    for (int j = 0; j < 4; j++) bfr[j] = *(const bf16x8*)&Bs[cur][boff + j * 16 * BK];
#pragma unroll
    for (int i = 0; i < 2; i++)
#pragma unroll
      for (int j = 0; j < 4; j++)
        acc[i][j] = __builtin_amdgcn_mfma_f32_16x16x32_bf16(af[i], bfr[j], acc[i][j], 0, 0, 0);
    cur = (cur == 2) ? 0 : cur + 1;
    nxt = (nxt == 2) ? 0 : nxt + 1;
  }
  // ---- fused epilogue ----
  const int crow0 = bm + wr * 32 + lhi * 4;
  const int bsel = (blockIdx.x >= 32) ? 1 : 0;
  const int hg = (bn >> 6) + wc;
  if (blockIdx.y >= 10) {
    u16* dst = vT_ + ((size_t)(bsel * KV_C + (hg - 20)) * 64) * T_C;
#pragma unroll
    for (int j = 0; j < 4; j++) {
      const int d = l15 + j * 16;
#pragma unroll
      for (int i = 0; i < 2; i++) {
        const int t2 = (crow0 + i * 16) & 2047;
        u16x4 pk;
#pragma unroll
        for (int r = 0; r < 4; r++) pk[r] = f2bf(acc[i][j][r]);
        *(u16x4*)&dst[(size_t)d * T_C + t2] = pk;
      }
    }
  } else {
    const bool isq = (blockIdx.y < 8);
    u16* dst = isq ? (qb_ + ((size_t)(bsel * H_C + hg) * T_C) * 64)
                   : (kb_ + ((size_t)(bsel * KV_C + (hg - 16)) * T_C) * 64);
    const float sc = isq ? (0.125f * 1.4426950408889634f) : 1.0f;
    const int par = l15 & 1;
#pragma unroll
    for (int j = 0; j < 4; j++) {
      const int d = l15 + j * 16;
      const int ir = (l15 >> 1) + j * 8;
#pragma unroll
      for (int i = 0; i < 2; i++)
#pragma unroll
        for (int r = 0; r < 4; r++) {
          const int t2 = (crow0 + i * 16 + r) & 2047;
          float v = acc[i][j][r];
          float p = __shfl_xor(v, 1, 64);
          f32x2 cs = tab[t2 * 32 + ir];
          float sgn = par ? cs.y : -cs.y;
          dst[(size_t)t2 * 64 + d] = f2bf((v * cs.x + p * sgn) * sc);
        }
    }
  }
}

// ---------- GEMM2: 64x64 tile (4 blocks/CU), 3-buf counted-vmcnt, T2 swizzle ----------
__global__ __launch_bounds__(256, 4) void k_gemm_bt(
    const u16* __restrict__ A, const u16* __restrict__ Bt, float* __restrict__ C,
    int M, int N, int K) {
  constexpr int BK = 32;
  __shared__ u16 As[3][64 * BK];
  __shared__ u16 Bs[3][64 * BK];
  const int tid = threadIdx.x;
  const int lane = tid & 63, wid = tid >> 6;
  const int wr = wid >> 1, wc = wid & 1;
  const int l15 = lane & 15, lhi = lane >> 4;
  const int bm = blockIdx.x * 64, bn = blockIdx.y * 64;
  const int srow = tid >> 2;
  const int scol = (((tid & 3) ^ ((tid >> 3) & 3))) * 8;
  const u16* ga = A + (size_t)(bm + srow) * K + scol;
  const u16* gb = Bt + (size_t)(bn + srow) * K + scol;
  f32x4 acc[2][2] = {};
  const int csw = (lhi ^ ((l15 >> 1) & 3)) * 8;
  const int aoff = (wr * 32 + l15) * BK + csw;
  const int boff = (wc * 32 + l15) * BK + csw;
  const int NT = K / BK;
#pragma unroll
  for (int p = 0; p < 2; p++) {
    GLL16(ga + p * BK, &As[p][tid * 8]);
    GLL16(gb + p * BK, &Bs[p][tid * 8]);
  }
  int cur = 0, nxt = 2;
  for (int k = 0; k < NT; ++k) {
    if (k + 1 < NT) asm volatile("s_waitcnt vmcnt(2)" ::: "memory");
    else            asm volatile("s_waitcnt vmcnt(0)" ::: "memory");
    __builtin_amdgcn_s_barrier();
    if (k + 2 < NT) {
      const int k2 = (k + 2) * BK;
      GLL16(ga + k2, &As[nxt][tid * 8]);
      GLL16(gb + k2, &Bs[nxt][tid * 8]);
    }
    bf16x8 af[2], bfr[2];
#pragma unroll
    for (int i = 0; i < 2; i++) af[i] = *(const bf16x8*)&As[cur][aoff + i * 16 * BK];
#pragma unroll
    for (int j = 0; j < 2; j++) bfr[j] = *(const bf16x8*)&Bs[cur][boff + j * 16 * BK];
#pragma unroll
    for (int i = 0; i < 2; i++)
#pragma unroll
      for (int j = 0; j < 2; j++)
        acc[i][j] = __builtin_amdgcn_mfma_f32_16x16x32_bf16(af[i], bfr[j], acc[i][j], 0, 0, 0);
    cur = (cur == 2) ? 0 : cur + 1;
    nxt = (nxt == 2) ? 0 : nxt + 1;
  }
  const int crow0 = bm + wr * 32 + lhi * 4, ccol0 = bn + wc * 32 + l15;
#pragma unroll
  for (int i = 0; i < 2; i++)
#pragma unroll
    for (int j = 0; j < 2; j++)
#pragma unroll
      for (int r = 0; r < 4; r++)
        C[(size_t)(crow0 + i * 16 + r) * N + ccol0 + j * 16] = acc[i][j][r];
}

// ---------- causal flash attention v9 = v5 + defer-max THR=8 (R16-proven) ----------
__global__ __launch_bounds__(256, 4) void k_attn(
    const u16* __restrict__ q_bf, const u16* __restrict__ k_bf,
    const u16* __restrict__ vT_bf, u16* __restrict__ att_bf) {
  __shared__ __align__(16) char lds[40960];
  const int bid = blockIdx.x;
  const int g = bid >> 5, g0 = g & 7, gs = g >> 3;
  const int qb = (gs == 0) ? (31 - g0) : (gs == 1) ? g0 : (gs == 2) ? (23 - g0) : (8 + g0);
  const int hb = bid & 31;
  const int h = hb & 15, b = hb >> 4;
  const int kvh = h >> 2;
  const int tid = threadIdx.x, lane = tid & 63, w = tid >> 6;
  const int l15 = lane & 15, lhi = lane >> 4;
  const u16* Qg = q_bf + ((size_t)((b * H_C + h) * T_C) + qb * 64) * 64;
  const u16* Kg = k_bf + ((size_t)((b * KV_C + kvh) * T_C)) * 64;
  const u16* Vg = vT_bf + (size_t)(b * KV_C + kvh) * 64 * T_C;  // [64][T]

  bf16x8 qf[2];
  const int qrow = w * 16 + l15;
#pragma unroll
  for (int kc = 0; kc < 2; kc++)
    qf[kc] = *(const bf16x8*)&Qg[(size_t)qrow * 64 + kc * 32 + lhi * 8];

  f32x4 o[4] = {};
  float m = -1e30f, lsum = 0.f;

  const int nt = qb + 1;
  const int r0 = tid >> 3, j0 = tid & 7;
  const int r1 = r0 + 32;
  const int wb0 = r0 * 128 + ((j0 * 16) ^ ((r0 & 7) << 4));
  const int wb1 = r1 * 128 + ((j0 * 16) ^ ((r1 & 7) << 4));
  char* psb = lds + 0x8000 + w * 0x800;
  const int psw = (l15 & 7) << 4;

  bf16x8 kr0, kr1, vr0, vr1;
  kr0 = *(const bf16x8*)&Kg[(size_t)r0 * 64 + j0 * 8];
  kr1 = *(const bf16x8*)&Kg[(size_t)r1 * 64 + j0 * 8];
  vr0 = *(const bf16x8*)&Vg[(size_t)r0 * T_C + j0 * 8];
  vr1 = *(const bf16x8*)&Vg[(size_t)r1 * T_C + j0 * 8];
  *(bf16x8*)(lds + wb0) = kr0;
  *(bf16x8*)(lds + wb1) = kr1;
  *(bf16x8*)(lds + 0x4000 + wb0) = vr0;
  *(bf16x8*)(lds + 0x4000 + wb1) = vr1;
  __syncthreads();

  for (int it = 0; it < nt; ++it) {
    const int t0 = it * 64;
    const int coff = (it & 1) * 0x2000;
    if (it + 1 < nt) {
      const int t1 = t0 + 64;
      kr0 = *(const bf16x8*)&Kg[(size_t)(t1 + r0) * 64 + j0 * 8];
      kr1 = *(const bf16x8*)&Kg[(size_t)(t1 + r1) * 64 + j0 * 8];
      vr0 = *(const bf16x8*)&Vg[(size_t)r0 * T_C + t1 + j0 * 8];
      vr1 = *(const bf16x8*)&Vg[(size_t)r1 * T_C + t1 + j0 * 8];
    }
    // ---- S^T = K Q^T (swapped operands; q = l15, key = nf*16+lhi*4+r) ----
    bf16x8 kf[4][2];
#pragma unroll
    for (int nf = 0; nf < 4; nf++)
#pragma unroll
      for (int kc = 0; kc < 2; kc++) {
        const int row = nf * 16 + l15;
        kf[nf][kc] = *(const bf16x8*)(lds + coff + row * 128 +
                                      ((kc * 64 + lhi * 16) ^ ((l15 & 7) << 4)));
      }
    f32x4 s[4] = {};
    __builtin_amdgcn_s_setprio(1);
#pragma unroll
    for (int nf = 0; nf < 4; nf++)
#pragma unroll
      for (int kc = 0; kc < 2; kc++)
        s[nf] = __builtin_amdgcn_mfma_f32_16x16x32_bf16(kf[nf][kc], qf[kc], s[nf], 0, 0, 0);
    __builtin_amdgcn_s_setprio(0);
    // ---- causal mask on diagonal tile: key > q ----
    if (it == nt - 1) {
      const int qg = w * 16 + l15;
#pragma unroll
      for (int nf = 0; nf < 4; nf++) {
        const int kb2 = nf * 16 + lhi * 4;
#pragma unroll
        for (int r = 0; r < 4; r++)
          if (kb2 + r > qg) s[nf][r] = -1e30f;
      }
    }
    // ---- online softmax: lane owns q-row; 2-shfl reduce over lhi ----
    float a0 = fmaxf(fmaxf(s[0][0], s[0][1]), fmaxf(s[0][2], s[0][3]));
    float a1 = fmaxf(fmaxf(s[1][0], s[1][1]), fmaxf(s[1][2], s[1][3]));
    float a2 = fmaxf(fmaxf(s[2][0], s[2][1]), fmaxf(s[2][2], s[2][3]));
    float a3 = fmaxf(fmaxf(s[3][0], s[3][1]), fmaxf(s[3][2], s[3][3]));
    float tmax = fmaxf(fmaxf(a0, a1), fmaxf(a2, a3));
    tmax = fmaxf(tmax, __shfl_xor(tmax, 16, 64));
    tmax = fmaxf(tmax, __shfl_xor(tmax, 32, 64));
    if (__any(tmax > m + 8.0f)) {  // defer-max: rescale only on real jumps
      float mn = fmaxf(m, tmax);
      float alpha = __builtin_exp2f(m - mn);
      m = mn;
      lsum *= alpha;
      float ar[4];
#pragma unroll
      for (int r = 0; r < 4; r++) ar[r] = __shfl(alpha, lhi * 4 + r, 64);
#pragma unroll
      for (int nf = 0; nf < 4; nf++)
#pragma unroll
        for (int r = 0; r < 4; r++) o[nf][r] *= ar[r];
    }
    // ---- P = exp2(S - m), pack bf16 pairs, 8x ds_write_b32 ----
#pragma unroll
    for (int nf = 0; nf < 4; nf++) {
      float p0 = __builtin_exp2f(s[nf][0] - m);
      float p1 = __builtin_exp2f(s[nf][1] - m);
      float p2 = __builtin_exp2f(s[nf][2] - m);
      float p3 = __builtin_exp2f(s[nf][3] - m);
      lsum += (p0 + p1) + (p2 + p3);
      unsigned lo = cvtpk(p0, p1), hi = cvtpk(p2, p3);
      const int pb = ((nf * 32 + lhi * 8) ^ psw) + l15 * 128;
      *(unsigned*)(psb + pb) = lo;
      *(unsigned*)(psb + pb + 4) = hi;
    }
    asm volatile("s_waitcnt lgkmcnt(0)" ::: "memory");
    __builtin_amdgcn_sched_barrier(0);
    // ---- O += P V ----
    __builtin_amdgcn_s_setprio(1);
#pragma unroll
    for (int kc = 0; kc < 2; kc++) {
      bf16x8 pa = *(const bf16x8*)(psb + l15 * 128 +
                                   ((kc * 64 + lhi * 16) ^ ((l15 & 7) << 4)));
#pragma unroll
      for (int nf = 0; nf < 4; nf++) {
        bf16x8 vf = *(const bf16x8*)(lds + 0x4000 + coff + (nf * 16 + l15) * 128 +
                                     ((kc * 64 + lhi * 16) ^ ((l15 & 7) << 4)));
        o[nf] = __builtin_amdgcn_mfma_f32_16x16x32_bf16(pa, vf, o[nf], 0, 0, 0);
      }
    }
    __builtin_amdgcn_s_setprio(0);
    if (it + 1 < nt) {
      const int noff = ((it + 1) & 1) * 0x2000;
      *(bf16x8*)(lds + noff + wb0) = kr0;
      *(bf16x8*)(lds + noff + wb1) = kr1;
      *(bf16x8*)(lds + 0x4000 + noff + wb0) = vr0;
      *(bf16x8*)(lds + 0x4000 + noff + wb1) = vr1;
    }
    __syncthreads();
  }
  // ---- epilogue: reduce lsum over lhi, redistribute inv to O rows ----
  lsum += __shfl_xor(lsum, 16, 64);
  lsum += __shfl_xor(lsum, 32, 64);
  float inv = 1.0f / lsum;
  float invr[4];
#pragma unroll
  for (int r = 0; r < 4; r++) invr[r] = __shfl(inv, lhi * 4 + r, 64);
  const int trow = qb * 64 + w * 16 + lhi * 4;
  const size_t obase = ((size_t)(b * T_C) + trow) * 1024 + h * 64;
#pragma unroll
  for (int nf = 0; nf < 4; nf++)
#pragma unroll
    for (int r = 0; r < 4; r++)
      att_bf[obase + (size_t)r * 1024 + nf * 16 + l15] = f2bf(o[nf][r] * invr[r]);
}

extern "C" void kernel_launch(void* const* d_in, const int* in_sizes, int n_in,
                              void* d_out, int out_size, void* d_ws, size_t ws_size,
                              hipStream_t stream) {
  const float* x  = (const float*)d_in[0];
  const float* wq = (const float*)d_in[2];
  const float* wk = (const float*)d_in[3];
  const float* wv = (const float*)d_in[4];
  const float* wo = (const float*)d_in[5];
  float* out = (float*)d_out;

  char* ws = (char*)d_ws;
  u16*   xb    = (u16*)(ws);                          //  8 MiB
  u16*   wqkvT = (u16*)(ws + (8ull  << 20));          //  3 MiB
  u16*   woT   = (u16*)(ws + (11ull << 20));          //  2 MiB
  u16*   vT_bf = (u16*)(ws + (13ull << 20));          //  2 MiB
  f32x2* tab   = (f32x2*)(ws + (15ull << 20));        // 512 KiB
  u16*   q_bf  = (u16*)(ws + (37ull << 20));          //  8 MiB
  u16*   k_bf  = (u16*)(ws + (45ull << 20));          //  2 MiB
  u16*   attb  = (u16*)(ws + (49ull << 20));          //  8 MiB

  k_prep<<<6912, 256, 0, stream>>>(x, xb, wq, wk, wv, wo, wqkvT, woT, tab);
  k_gemm_qkv<<<dim3(64, 12), 256, 0, stream>>>(xb, wqkvT, tab, q_bf, k_bf, vT_bf);
  k_attn<<<1024, 256, 0, stream>>>(q_bf, k_bf, vT_bf, attb);
  k_gemm_bt<<<dim3(64, 16), 256, 0, stream>>>(attb, woT, out, 4096, 1024, 1024);
}